// Round 9
// baseline (726.149 us; speedup 1.0000x reference)
//
#include <hip/hip_runtime.h>
#include <hip/hip_bf16.h>
#include <math.h>

#define BATCH 4
#define XL 128
#define YL 1024
#define DMODEL 512
#define NH 8
#define NLAYER 3
#define DFF 2048
#define MASK_ID 1024
#define EOS_TOK 1024
#define HD 64
#define SEQ 1153          // XL + 1 + YL
#define SEQP 1216         // 19*64, padded k-extent for V^T
#define OV 1025
#define NEGBIG (-1e9f)
#define QBLK 128
#define CCAP 2432         // max compacted masked rows

typedef unsigned short u16;
typedef unsigned int u32;
typedef short short8 __attribute__((ext_vector_type(8)));
typedef float f32x4 __attribute__((ext_vector_type(4)));

__device__ __forceinline__ u16 f2bf(float f) {
    union { float f; unsigned u; } v; v.f = f;
    unsigned r = v.u + 0x7fffu + ((v.u >> 16) & 1u);   // RNE
    return (u16)(r >> 16);
}
__device__ __forceinline__ float bf2f(u16 b) {
    union { unsigned u; float f; } v; v.u = ((unsigned)b) << 16;
    return v.f;
}

// ---------------- fused f32 -> bf16 convert for all 5 weight tensors ----------------
__global__ __launch_bounds__(256) void cvt5_kernel(
    const float* __restrict__ s0, u16* __restrict__ d0, int n0,
    const float* __restrict__ s1, u16* __restrict__ d1, int n1,
    const float* __restrict__ s2, u16* __restrict__ d2, int n2,
    const float* __restrict__ s3, u16* __restrict__ d3, int n3,
    const float* __restrict__ s4, u16* __restrict__ d4, int n4)
{
    int c0 = n0, c1 = c0 + n1, c2 = c1 + n2, c3 = c2 + n3, c4 = c3 + n4;
    for (int i = blockIdx.x * 256 + threadIdx.x; i < c4; i += gridDim.x * 256) {
        const float* s; u16* d; int j;
        if (i < c0)      { s = s0; d = d0; j = i; }
        else if (i < c1) { s = s1; d = d1; j = i - c0; }
        else if (i < c2) { s = s2; d = d2; j = i - c1; }
        else if (i < c3) { s = s3; d = d3; j = i - c2; }
        else             { s = s4; d = d4; j = i - c3; }
        float4 v = ((const float4*)s)[j];
        ushort4 o;
        o.x = f2bf(v.x); o.y = f2bf(v.y); o.z = f2bf(v.z); o.w = f2bf(v.w);
        ((ushort4*)d)[j] = o;
    }
}

// ---------------- emo rows ----------------
__global__ __launch_bounds__(256) void emo_kernel(
    const float* __restrict__ emo_feature, const float* __restrict__ emo_W,
    const float* __restrict__ emo_b, const float* __restrict__ type_emb,
    float* __restrict__ hbuf, u16* __restrict__ hbuf_bf)
{
    int b = blockIdx.x >> 3, c = blockIdx.x & 7;
    int t = threadIdx.x;
    int osub = t >> 2, ln = t & 3;
    int d = c * 64 + osub;
    const float* f = emo_feature + b * 768 + ln * 192;
    const float* w = emo_W + (size_t)d * 768 + ln * 192;
    float acc = 0.f;
    #pragma unroll 4
    for (int k = 0; k < 192; ++k) acc = fmaf(f[k], w[k], acc);
    acc += __shfl_xor(acc, 1);
    acc += __shfl_xor(acc, 2);
    if (ln == 0) {
        float v = acc + emo_b[d] + type_emb[DMODEL + d];
        hbuf[(size_t)(b * SEQ + XL) * DMODEL + d] = v;
        hbuf_bf[(size_t)(b * SEQ + XL) * DMODEL + d] = f2bf(v);
    }
}

// ---------------- build h_input (x & y rows), wave-per-row ----------------
__global__ __launch_bounds__(256) void build_h_kernel(
    const int* __restrict__ x, const int* __restrict__ y, const int* __restrict__ y_mask,
    const float* __restrict__ text_emb, const float* __restrict__ audio_emb,
    const float* __restrict__ type_emb,
    const float* __restrict__ alpha_text, const float* __restrict__ alpha_audio,
    float* __restrict__ hbuf, u16* __restrict__ hbuf_bf)
{
    int row = blockIdx.x * 4 + (threadIdx.x >> 6);
    int l = threadIdx.x & 63;
    int b = row / SEQ, s = row % SEQ;
    if (s == XL) return;
    int d0 = l * 8;

    const float* emb; const float* te; float alpha; int pos;
    if (s < XL) {
        int tok = x[b * XL + s];
        emb = text_emb + (size_t)tok * DMODEL;
        te = type_emb; alpha = alpha_text[0]; pos = s;
    } else {
        int r = s - XL - 1;
        int tok = y_mask[b * YL + r] ? MASK_ID : y[b * YL + r];
        emb = audio_emb + (size_t)tok * DMODEL;
        te = type_emb + 2 * DMODEL; alpha = alpha_audio[0]; pos = r;
    }

    float4 e0 = *(const float4*)(emb + d0);
    float4 e1 = *(const float4*)(emb + d0 + 4);
    float4 t0 = *(const float4*)(te + d0);
    float4 t1 = *(const float4*)(te + d0 + 4);
    float v[8] = {e0.x + t0.x, e0.y + t0.y, e0.z + t0.z, e0.w + t0.w,
                  e1.x + t1.x, e1.y + t1.y, e1.z + t1.z, e1.w + t1.w};
    float fp = (float)pos;
    #pragma unroll
    for (int p = 0; p < 4; ++p) {
        int d = d0 + 2 * p;
        float div = __expf((float)d * (-9.210340371976184f / (float)DMODEL));
        float sn, cs;
        __sincosf(fp * div, &sn, &cs);
        v[2 * p]     += alpha * sn;
        v[2 * p + 1] += alpha * cs;
    }

    float* hp = hbuf + (size_t)row * DMODEL + d0;
    *(float4*)hp       = make_float4(v[0], v[1], v[2], v[3]);
    *(float4*)(hp + 4) = make_float4(v[4], v[5], v[6], v[7]);
    short8 sv;
    #pragma unroll
    for (int e = 0; e < 8; ++e) sv[e] = (short)f2bf(v[e]);
    *(short8*)(hbuf_bf + (size_t)row * DMODEL + d0) = sv;
}

// ---------------- bf16 MFMA NT GEMM (full-K) ----------
__global__ __launch_bounds__(256) void gemm_bf16_kernel(
    const u16* __restrict__ A, const u16* __restrict__ Bw,
    const float* __restrict__ bias,
    float* __restrict__ Cf, u16* __restrict__ Cb,
    int M, int N, int K, int relu)
{
    __shared__ u16 As[128 * 32];
    __shared__ u16 Bs[128 * 32];
    int tid = threadIdx.x;
    int w = tid >> 6, l = tid & 63;
    int m0 = blockIdx.y * 128, n0 = blockIdx.x * 128;
    int wm = (w >> 1) * 64, wn = (w & 1) * 64;

    f32x4 acc[4][4];
    #pragma unroll
    for (int i = 0; i < 4; ++i)
        #pragma unroll
        for (int j = 0; j < 4; ++j) acc[i][j] = (f32x4){0.f, 0.f, 0.f, 0.f};

    int srow0 = (w << 5) + (l >> 2);
    int skp = (l & 3) << 3;

    for (int k0 = 0; k0 < K; k0 += 32) {
        #pragma unroll
        for (int c = 0; c < 2; ++c) {
            int row = srow0 + c * 16;
            int am = m0 + row; if (am >= M) am = M - 1;
            int bn = n0 + row; if (bn >= N) bn = N - 1;
            __builtin_amdgcn_global_load_lds(
                (const __attribute__((address_space(1))) void*)(A + (size_t)am * K + k0 + skp),
                (__attribute__((address_space(3))) void*)(As + ((w * 2 + c) << 9)), 16, 0, 0);
            __builtin_amdgcn_global_load_lds(
                (const __attribute__((address_space(1))) void*)(Bw + (size_t)bn * K + k0 + skp),
                (__attribute__((address_space(3))) void*)(Bs + ((w * 2 + c) << 9)), 16, 0, 0);
        }
        __syncthreads();
        short8 af[4], bfr[4];
        #pragma unroll
        for (int i = 0; i < 4; ++i) {
            af[i]  = *(const short8*)(As + (wm + i * 16 + (l & 15)) * 32 + ((l >> 4) << 3));
            bfr[i] = *(const short8*)(Bs + (wn + i * 16 + (l & 15)) * 32 + ((l >> 4) << 3));
        }
        #pragma unroll
        for (int i = 0; i < 4; ++i)
            #pragma unroll
            for (int j = 0; j < 4; ++j)
                acc[i][j] = __builtin_amdgcn_mfma_f32_16x16x32_bf16(af[i], bfr[j], acc[i][j], 0, 0, 0);
        __syncthreads();
    }

    #pragma unroll
    for (int i = 0; i < 4; ++i) {
        #pragma unroll
        for (int j = 0; j < 4; ++j) {
            #pragma unroll
            for (int jj = 0; jj < 4; ++jj) {
                int row = m0 + wm + i * 16 + ((l >> 4) << 2) + jj;
                int col = n0 + wn + j * 16 + (l & 15);
                if (row < M && col < N) {
                    float v = acc[i][j][jj];
                    if (bias) v += bias[col];
                    if (relu) v = fmaxf(v, 0.f);
                    if (Cf) Cf[(size_t)row * N + col] = v;
                    if (Cb) Cb[(size_t)row * N + col] = f2bf(v);
                }
            }
        }
    }
}

// ---- split-K variant ----
__global__ __launch_bounds__(256) void gemm_bf16_splitk_kernel(
    const u16* __restrict__ A, const u16* __restrict__ Bw,
    float* __restrict__ P0, float* __restrict__ P1, float* __restrict__ P2,
    int M, int N, int K, int klen)
{
    __shared__ u16 As[128 * 32];
    __shared__ u16 Bs[128 * 32];
    int tid = threadIdx.x;
    int w = tid >> 6, l = tid & 63;
    int z = blockIdx.z;
    float* Cp = (z == 0) ? P0 : (z == 1) ? P1 : P2;
    int kbeg = z * klen;
    int kend = min(kbeg + klen, K);
    int m0 = blockIdx.y * 128, n0 = blockIdx.x * 128;
    int wm = (w >> 1) * 64, wn = (w & 1) * 64;

    f32x4 acc[4][4];
    #pragma unroll
    for (int i = 0; i < 4; ++i)
        #pragma unroll
        for (int j = 0; j < 4; ++j) acc[i][j] = (f32x4){0.f, 0.f, 0.f, 0.f};

    int srow0 = (w << 5) + (l >> 2);
    int skp = (l & 3) << 3;

    for (int k0 = kbeg; k0 < kend; k0 += 32) {
        #pragma unroll
        for (int c = 0; c < 2; ++c) {
            int row = srow0 + c * 16;
            int am = m0 + row; if (am >= M) am = M - 1;
            int bn = n0 + row; if (bn >= N) bn = N - 1;
            __builtin_amdgcn_global_load_lds(
                (const __attribute__((address_space(1))) void*)(A + (size_t)am * K + k0 + skp),
                (__attribute__((address_space(3))) void*)(As + ((w * 2 + c) << 9)), 16, 0, 0);
            __builtin_amdgcn_global_load_lds(
                (const __attribute__((address_space(1))) void*)(Bw + (size_t)bn * K + k0 + skp),
                (__attribute__((address_space(3))) void*)(Bs + ((w * 2 + c) << 9)), 16, 0, 0);
        }
        __syncthreads();
        short8 af[4], bfr[4];
        #pragma unroll
        for (int i = 0; i < 4; ++i) {
            af[i]  = *(const short8*)(As + (wm + i * 16 + (l & 15)) * 32 + ((l >> 4) << 3));
            bfr[i] = *(const short8*)(Bs + (wn + i * 16 + (l & 15)) * 32 + ((l >> 4) << 3));
        }
        #pragma unroll
        for (int i = 0; i < 4; ++i)
            #pragma unroll
            for (int j = 0; j < 4; ++j)
                acc[i][j] = __builtin_amdgcn_mfma_f32_16x16x32_bf16(af[i], bfr[j], acc[i][j], 0, 0, 0);
        __syncthreads();
    }

    #pragma unroll
    for (int i = 0; i < 4; ++i) {
        #pragma unroll
        for (int j = 0; j < 4; ++j) {
            #pragma unroll
            for (int jj = 0; jj < 4; ++jj) {
                int row = m0 + wm + i * 16 + ((l >> 4) << 2) + jj;
                int col = n0 + wn + j * 16 + (l & 15);
                if (row < M && col < N)
                    Cp[(size_t)row * N + col] = acc[i][j][jj];
            }
        }
    }
}

// ---- split-K + dynamic-M (logits) ----
__global__ __launch_bounds__(256) void gemm_bf16_splitk_dynm_kernel(
    const u16* __restrict__ A, const u16* __restrict__ Bw,
    const int* __restrict__ Mp,
    float* __restrict__ P0, float* __restrict__ P1,
    int N, int K, int klen)
{
    int M = *Mp;
    int m0 = blockIdx.y * 128;
    if (m0 >= M) return;
    __shared__ u16 As[128 * 32];
    __shared__ u16 Bs[128 * 32];
    int tid = threadIdx.x;
    int w = tid >> 6, l = tid & 63;
    int z = blockIdx.z;
    float* Cp = (z == 0) ? P0 : P1;
    int kbeg = z * klen;
    int kend = min(kbeg + klen, K);
    int n0 = blockIdx.x * 128;
    int wm = (w >> 1) * 64, wn = (w & 1) * 64;

    f32x4 acc[4][4];
    #pragma unroll
    for (int i = 0; i < 4; ++i)
        #pragma unroll
        for (int j = 0; j < 4; ++j) acc[i][j] = (f32x4){0.f, 0.f, 0.f, 0.f};

    int srow0 = (w << 5) + (l >> 2);
    int skp = (l & 3) << 3;

    for (int k0 = kbeg; k0 < kend; k0 += 32) {
        #pragma unroll
        for (int c = 0; c < 2; ++c) {
            int row = srow0 + c * 16;
            int am = m0 + row; if (am >= M) am = M - 1;
            int bn = n0 + row; if (bn >= N) bn = N - 1;
            __builtin_amdgcn_global_load_lds(
                (const __attribute__((address_space(1))) void*)(A + (size_t)am * K + k0 + skp),
                (__attribute__((address_space(3))) void*)(As + ((w * 2 + c) << 9)), 16, 0, 0);
            __builtin_amdgcn_global_load_lds(
                (const __attribute__((address_space(1))) void*)(Bw + (size_t)bn * K + k0 + skp),
                (__attribute__((address_space(3))) void*)(Bs + ((w * 2 + c) << 9)), 16, 0, 0);
        }
        __syncthreads();
        short8 af[4], bfr[4];
        #pragma unroll
        for (int i = 0; i < 4; ++i) {
            af[i]  = *(const short8*)(As + (wm + i * 16 + (l & 15)) * 32 + ((l >> 4) << 3));
            bfr[i] = *(const short8*)(Bs + (wn + i * 16 + (l & 15)) * 32 + ((l >> 4) << 3));
        }
        #pragma unroll
        for (int i = 0; i < 4; ++i)
            #pragma unroll
            for (int j = 0; j < 4; ++j)
                acc[i][j] = __builtin_amdgcn_mfma_f32_16x16x32_bf16(af[i], bfr[j], acc[i][j], 0, 0, 0);
        __syncthreads();
    }

    #pragma unroll
    for (int i = 0; i < 4; ++i) {
        #pragma unroll
        for (int j = 0; j < 4; ++j) {
            #pragma unroll
            for (int jj = 0; jj < 4; ++jj) {
                int row = m0 + wm + i * 16 + ((l >> 4) << 2) + jj;
                int col = n0 + wn + j * 16 + (l & 15);
                if (row < M && col < N)
                    Cp[(size_t)row * N + col] = acc[i][j][jj];
            }
        }
    }
}

// ---------------- V transpose: qkv V-part -> vt[bh][d][k], zero-padded to SEQP ----------------
// grid (19, 32), 256 thr
__global__ __launch_bounds__(256) void vtrans_kernel(
    const u16* __restrict__ qkv, u16* __restrict__ vt)
{
    __shared__ u16 tbuf[64][72];
    int bh = blockIdx.y;
    int b = bh >> 3, h = bh & 7;
    int kt = blockIdx.x;
    int tid = threadIdx.x;
    #pragma unroll
    for (int i = 0; i < 2; ++i) {
        int idx = tid + i * 256;
        int r = idx >> 3, d0 = (idx & 7) << 3;
        int s = kt * 64 + r;
        short8 v = (short8){0,0,0,0,0,0,0,0};
        if (s < SEQ)
            v = *(const short8*)(qkv + (size_t)(b * SEQ + s) * 1536 + 1024 + h * 64 + d0);
        *(short8*)&tbuf[r][d0] = v;
    }
    __syncthreads();
    u16* out = vt + (size_t)bh * 64 * SEQP + kt * 64;
    #pragma unroll
    for (int i = 0; i < 2; ++i) {
        int idx = tid + i * 256;
        int d = idx >> 3, s0 = (idx & 7) << 3;
        short8 v;
        #pragma unroll
        for (int e = 0; e < 8; ++e) v[e] = (short)tbuf[s0 + e][d];
        *(short8*)(out + (size_t)d * SEQP + s0) = v;
    }
}

// ============== MFMA flash attention: swapped QK^T, in-register softmax, =============
// ============== NO K/V LDS staging — direct global frag loads (L1/L2 resident) =======
// grid (10, 32), 512 thr = 8 waves; wave w owns q rows [q0+16w, q0+16w+16).
__global__ __launch_bounds__(512) void attn_mfma_kernel(
    const u16* __restrict__ qkv, const u16* __restrict__ vt,
    const int* __restrict__ x1_lens, const int* __restrict__ x2_lens,
    const int* __restrict__ y1_lens, const int* __restrict__ y2_lens,
    const int* __restrict__ y_mask,
    u16* __restrict__ obuf)
{
    __shared__ unsigned long long Bits[7][19];  // per-rowtype per-tile allow bitmap

    int tid = threadIdx.x;
    int w = tid >> 6, l = tid & 63;
    int g = l >> 4;                 // lane group 0..3
    int q = l & 15;                 // q-row within wave tile / frag row
    int bh = blockIdx.y;
    int b = bh >> 3, h = bh & 7;
    int q0 = (gridDim.x - 1 - blockIdx.x) * QBLK;   // heavy tiles first

    int x1 = x1_lens[b], xlen = x1 + 1 + x2_lens[b];
    int y1 = y1_lens[b], ylen = y1 + 1 + y2_lens[b];

    // ---- block-level kmax over alive rows; early-exit fully-dead blocks ----
    int kmax = -1;
    if (q0 < XL) kmax = max(kmax, xlen - 1);
    if (XL >= q0 && XL < q0 + QBLK) kmax = max(kmax, XL);
    {
        int ry0 = max(0, q0 - XL - 1);
        int ry1 = min(YL - 1, q0 + QBLK - 2 - XL);
        if (ry0 <= ry1) {
            if (ry0 <= y1 - 1) kmax = max(kmax, XL + y1);
            if (y1 >= ry0 && y1 <= ry1) kmax = max(kmax, XL + y1 + 1);
            int a = max(ry0, y1 + 1), bb = min(ry1, ylen - 1);
            if (a <= bb) kmax = max(kmax, XL + ylen);
        }
    }
    if (kmax < 0) return;
    int NKT = (kmax >> 6) + 1;

    // ---- allow bitmaps via wave ballot ----
    for (int pp = w; pp < 7 * 19; pp += 8) {
        int ty = pp / 19, tile = pp - ty * 19;
        int c = tile * 64 + l;
        bool allow = false;
        if (c < SEQ && ty < 6) {
            bool a2c = (c == XL), ygt = (c > XL);
            if (ty == 0) allow = (c < x1);
            else if (ty == 1) allow = (c >= x1) && (c < xlen);
            else if (ty == 2) allow = a2c;
            else if (ty == 3) allow = (c < x1) || (ygt && c <= XL + y1);
            else if (ty == 4) allow = (c < xlen) || a2c || (ygt && c <= XL + y1 + 1);
            else {
                int ym = ygt ? y_mask[b * YL + c - XL - 1] : 0;
                allow = (((c < xlen) || a2c || (ygt && c <= XL + ylen)) && !ym);
            }
        }
        unsigned long long mk = __ballot(allow);
        if (l == 0) Bits[ty][tile] = mk;
    }
    __syncthreads();

    // ---- Q fragment (q = l&15), scale 1/8 folded in ----
    int qr = q0 + w * 16 + q;
    int qrc = min(qr, SEQ - 1);
    short8 qf0, qf1;
    {
        const u16* qp = qkv + (size_t)(b * SEQ + qrc) * 1536 + h * 64 + (g << 3);
        short8 r0 = *(const short8*)qp;
        short8 r1 = *(const short8*)(qp + 32);
        #pragma unroll
        for (int e = 0; e < 8; ++e) {
            qf0[e] = (short)f2bf(bf2f((u16)r0[e]) * 0.125f);
            qf1[e] = (short)f2bf(bf2f((u16)r1[e]) * 0.125f);
        }
    }

    // ---- row type of this lane's q ----
    int rt;
    {
        if (qr >= SEQ) rt = 6;
        else if (qr < XL) rt = (qr < x1) ? 0 : 1;
        else if (qr == XL) rt = 2;
        else {
            int ry = qr - XL - 1;
            rt = (ry < y1) ? 3 : (ry == y1) ? 4 : (ry < ylen) ? 5 : 6;
        }
    }

    f32x4 oacc[4];
    #pragma unroll
    for (int db = 0; db < 4; ++db) oacc[db] = (f32x4){0.f, 0.f, 0.f, 0.f};
    float mrun = -INFINITY, lrun = 0.f;

    int srcA = q + ((g & 1) << 5);
    int srcB = srcA + 16;
    bool hi = (g >> 1) & 1;

    const u16* kbase = qkv + (size_t)b * SEQ * 1536 + 512 + h * 64 + (g << 3);
    const u16* vbase = vt + (size_t)bh * 64 * SEQP + (size_t)q * SEQP + (g << 3);

    for (int kt = 0; kt < NKT; ++kt) {
        // ---- K fragments: direct global 16B loads (lane = exact A-frag) ----
        short8 kf0[4], kf1[4];
        #pragma unroll
        for (int cb = 0; cb < 4; ++cb) {
            int ks = min(kt * 64 + cb * 16 + q, SEQ - 1);
            const u16* kp = kbase + (size_t)ks * 1536;
            kf0[cb] = *(const short8*)kp;
            kf1[cb] = *(const short8*)(kp + 32);
        }
        // ---- V fragments: direct global 16B loads from V^T (lane = exact B-frag) ----
        short8 vf0[4], vf1[4];
        #pragma unroll
        for (int db = 0; db < 4; ++db) {
            const u16* vp = vbase + (size_t)(db * 16) * SEQP + kt * 64;
            vf0[db] = *(const short8*)vp;
            vf1[db] = *(const short8*)(vp + 32);
        }

        // ---- QK^T swapped: sc[cb][reg] = S^T[k = 16cb+4g+reg][q] ----
        f32x4 sc[4];
        __builtin_amdgcn_s_setprio(1);
        #pragma unroll
        for (int cb = 0; cb < 4; ++cb) {
            f32x4 z = (f32x4){0.f, 0.f, 0.f, 0.f};
            z = __builtin_amdgcn_mfma_f32_16x16x32_bf16(kf0[cb], qf0, z, 0, 0, 0);
            sc[cb] = __builtin_amdgcn_mfma_f32_16x16x32_bf16(kf1[cb], qf1, z, 0, 0, 0);
        }
        __builtin_amdgcn_s_setprio(0);

        // ---- mask via bitmap ----
        unsigned long long mb = Bits[rt][kt];
        #pragma unroll
        for (int cb = 0; cb < 4; ++cb) {
            unsigned nib = (unsigned)(mb >> (16 * cb + 4 * g)) & 0xFu;
            #pragma unroll
            for (int r = 0; r < 4; ++r)
                sc[cb][r] = ((nib >> r) & 1u) ? sc[cb][r] : NEGBIG;
        }

        // ---- in-register online softmax (one q-row per lane) ----
        float tmax = sc[0][0];
        #pragma unroll
        for (int cb = 0; cb < 4; ++cb)
            #pragma unroll
            for (int r = 0; r < 4; ++r) tmax = fmaxf(tmax, sc[cb][r]);
        tmax = fmaxf(tmax, __shfl_xor(tmax, 16));
        tmax = fmaxf(tmax, __shfl_xor(tmax, 32));
        float newm = fmaxf(mrun, tmax);
        float corr = __expf(mrun - newm);
        float p[4][4];
        float ps = 0.f;
        #pragma unroll
        for (int cb = 0; cb < 4; ++cb)
            #pragma unroll
            for (int r = 0; r < 4; ++r) {
                p[cb][r] = __expf(sc[cb][r] - newm);
                ps += p[cb][r];
            }
        ps += __shfl_xor(ps, 16);
        ps += __shfl_xor(ps, 32);
        lrun = lrun * corr + ps;
        mrun = newm;

        // ---- rescale O (lane holds O rows 4g+r) ----
        float cr[4];
        #pragma unroll
        for (int r = 0; r < 4; ++r) cr[r] = __shfl(corr, (g << 2) + r);
        #pragma unroll
        for (int db = 0; db < 4; ++db)
            #pragma unroll
            for (int r = 0; r < 4; ++r) oacc[db][r] *= cr[r];

        // ---- pack P to bf16 pairs ----
        u32 P0[4], P1[4];
        #pragma unroll
        for (int cb = 0; cb < 4; ++cb) {
            P0[cb] = (u32)f2bf(p[cb][0]) | ((u32)f2bf(p[cb][1]) << 16);
            P1[cb] = (u32)f2bf(p[cb][2]) | ((u32)f2bf(p[cb][3]) << 16);
        }

        // ---- exchange -> A-fragments for PV ----
        union { u32 u[4]; short8 s; } f1, f2;
        {
            u32 a0 = __shfl(P0[0], srcA), a1 = __shfl(P1[0], srcA);
            u32 a2 = __shfl(P0[0], srcB), a3 = __shfl(P1[0], srcB);
            u32 b0 = __shfl(P0[1], srcA), b1 = __shfl(P1[1], srcA);
            u32 b2 = __shfl(P0[1], srcB), b3 = __shfl(P1[1], srcB);
            f1.u[0] = hi ? b0 : a0; f1.u[1] = hi ? b1 : a1;
            f1.u[2] = hi ? b2 : a2; f1.u[3] = hi ? b3 : a3;
            u32 c0 = __shfl(P0[2], srcA), c1 = __shfl(P1[2], srcA);
            u32 c2 = __shfl(P0[2], srcB), c3 = __shfl(P1[2], srcB);
            u32 d0 = __shfl(P0[3], srcA), d1 = __shfl(P1[3], srcA);
            u32 d2 = __shfl(P0[3], srcB), d3 = __shfl(P1[3], srcB);
            f2.u[0] = hi ? d0 : c0; f2.u[1] = hi ? d1 : c1;
            f2.u[2] = hi ? d2 : c2; f2.u[3] = hi ? d3 : c3;
        }

        // ---- PV: O[q=4g+r][d] += P V ----
        __builtin_amdgcn_s_setprio(1);
        #pragma unroll
        for (int db = 0; db < 4; ++db) {
            oacc[db] = __builtin_amdgcn_mfma_f32_16x16x32_bf16(f1.s, vf0[db], oacc[db], 0, 0, 0);
            oacc[db] = __builtin_amdgcn_mfma_f32_16x16x32_bf16(f2.s, vf1[db], oacc[db], 0, 0, 0);
        }
        __builtin_amdgcn_s_setprio(0);
    }

    // ---- normalize + write ----
    float rinv = 1.f / lrun;
    float rl[4];
    #pragma unroll
    for (int r = 0; r < 4; ++r) rl[r] = __shfl(rinv, (g << 2) + r);
    #pragma unroll
    for (int db = 0; db < 4; ++db) {
        #pragma unroll
        for (int r = 0; r < 4; ++r) {
            int qrj = q0 + w * 16 + (g << 2) + r;
            if (qrj < SEQ)
                obuf[(size_t)(b * SEQ + qrj) * DMODEL + h * 64 + db * 16 + q] =
                    f2bf(oacc[db][r] * rl[r]);
        }
    }
}

// ------- residual add + fused split-K reduce (+bias) + LayerNorm, wave-per-row -------
__global__ __launch_bounds__(256) void add_ln_kernel(
    float* __restrict__ hbuf, u16* __restrict__ hbuf_bf,
    const float* __restrict__ p0, const float* __restrict__ p1,
    const float* __restrict__ p2, const float* __restrict__ bias,
    const float* __restrict__ g, const float* __restrict__ beta)
{
    int row = blockIdx.x * 4 + (threadIdx.x >> 6);
    int l = threadIdx.x & 63;
    int d0 = l * 8;
    size_t off = (size_t)row * DMODEL + d0;
    float* hp = hbuf + off;
    float4 a0 = *(const float4*)hp, a1 = *(const float4*)(hp + 4);
    float4 q0 = *(const float4*)(p0 + off), q1 = *(const float4*)(p0 + off + 4);
    float v[8] = {a0.x + q0.x, a0.y + q0.y, a0.z + q0.z, a0.w + q0.w,
                  a1.x + q1.x, a1.y + q1.y, a1.z + q1.z, a1.w + q1.w};
    if (p1) {
        float4 r0 = *(const float4*)(p1 + off), r1 = *(const float4*)(p1 + off + 4);
        v[0] += r0.x; v[1] += r0.y; v[2] += r0.z; v[3] += r0.w;
        v[4] += r1.x; v[5] += r1.y; v[6] += r1.z; v[7] += r1.w;
    }
    if (p2) {
        float4 r0 = *(const float4*)(p2 + off), r1 = *(const float4*)(p2 + off + 4);
        v[0] += r0.x; v[1] += r0.y; v[2] += r0.z; v[3] += r0.w;
        v[4] += r1.x; v[5] += r1.y; v[6] += r1.z; v[7] += r1.w;
    }
    {
        float4 b0 = *(const float4*)(bias + d0), b1 = *(const float4*)(bias + d0 + 4);
        v[0] += b0.x; v[1] += b0.y; v[2] += b0.z; v[3] += b0.w;
        v[4] += b1.x; v[5] += b1.y; v[6] += b1.z; v[7] += b1.w;
    }
    float s = 0.f;
    #pragma unroll
    for (int e = 0; e < 8; ++e) s += v[e];
    #pragma unroll
    for (int off2 = 32; off2 > 0; off2 >>= 1) s += __shfl_xor(s, off2);
    float mu = s * (1.f / DMODEL);
    float sq = 0.f;
    #pragma unroll
    for (int e = 0; e < 8; ++e) { v[e] -= mu; sq += v[e] * v[e]; }
    #pragma unroll
    for (int off2 = 32; off2 > 0; off2 >>= 1) sq += __shfl_xor(sq, off2);
    float inv = 1.f / sqrtf(sq * (1.f / DMODEL) + 1e-5f);
    float4 g0 = *(const float4*)(g + d0), g1 = *(const float4*)(g + d0 + 4);
    float4 be0 = *(const float4*)(beta + d0), be1 = *(const float4*)(beta + d0 + 4);
    float o[8];
    o[0] = v[0] * inv * g0.x + be0.x; o[1] = v[1] * inv * g0.y + be0.y;
    o[2] = v[2] * inv * g0.z + be0.z; o[3] = v[3] * inv * g0.w + be0.w;
    o[4] = v[4] * inv * g1.x + be1.x; o[5] = v[5] * inv * g1.y + be1.y;
    o[6] = v[6] * inv * g1.z + be1.z; o[7] = v[7] * inv * g1.w + be1.w;
    *(float4*)hp       = make_float4(o[0], o[1], o[2], o[3]);
    *(float4*)(hp + 4) = make_float4(o[4], o[5], o[6], o[7]);
    short8 sv;
    #pragma unroll
    for (int e = 0; e < 8; ++e) sv[e] = (short)f2bf(o[e]);
    *(short8*)(hbuf_bf + off) = sv;
}

// ---------------- compaction of masked rows ----------------
__global__ __launch_bounds__(256) void init_accum_kernel(float* accum) {
    if (threadIdx.x < 8) accum[threadIdx.x] = 0.f;
}

__global__ __launch_bounds__(256) void compact_kernel(
    const int* __restrict__ y_mask, int* __restrict__ cnt, int* __restrict__ cmap)
{
    int i = blockIdx.x * 256 + threadIdx.x;
    if (i < BATCH * YL && y_mask[i]) {
        int pos = atomicAdd(cnt, 1);
        cmap[pos] = i;
    }
}

__global__ __launch_bounds__(256) void copy_rows_kernel(
    const int* __restrict__ cnt, const int* __restrict__ cmap,
    const u16* __restrict__ hbuf_bf, const int* __restrict__ y,
    u16* __restrict__ cbuf, int* __restrict__ ctgt)
{
    int i = blockIdx.x;
    if (i >= *cnt) return;
    int g = cmap[i];
    int b = g >> 10, r = g & 1023;
    const u16* src = hbuf_bf + (size_t)(b * SEQ + XL + 1 + r) * DMODEL;
    u16* dst = cbuf + (size_t)i * DMODEL;
    int t = threadIdx.x;
    ((ushort2*)dst)[t] = ((const ushort2*)src)[t];
    if (t == 0) ctgt[i] = y[g];
}

// ---------------- CE + top-3 over compacted rows (sums 2 logits partials) ----------------
__global__ __launch_bounds__(256) void ce_kernel(
    const int* __restrict__ cnt,
    const float* __restrict__ lg0, const float* __restrict__ lg1,
    const int* __restrict__ ctgt, float* __restrict__ accum)
{
    int row = blockIdx.x;
    if (row >= *cnt) return;
    const float* lp0 = lg0 + (size_t)row * OV;
    const float* lp1 = lg1 + (size_t)row * OV;
    int tgt = ctgt[row];
    int t = threadIdx.x;
    __shared__ float red[4];

    float lmax = -INFINITY;
    for (int i = t; i < OV; i += 256) lmax = fmaxf(lmax, lp0[i] + lp1[i]);
    #pragma unroll
    for (int off = 32; off > 0; off >>= 1) lmax = fmaxf(lmax, __shfl_xor(lmax, off));
    if ((t & 63) == 0) red[t >> 6] = lmax;
    __syncthreads();
    lmax = fmaxf(fmaxf(red[0], red[1]), fmaxf(red[2], red[3]));
    __syncthreads();

    float lsum = 0.f;
    for (int i = t; i < OV; i += 256) lsum += expf(lp0[i] + lp1[i] - lmax);
    #pragma unroll
    for (int off = 32; off > 0; off >>= 1) lsum += __shfl_xor(lsum, off);
    if ((t & 63) == 0) red[t >> 6] = lsum;
    __syncthreads();
    lsum = red[0] + red[1] + red[2] + red[3];
    __syncthreads();

    float lt = lp0[tgt] + lp1[tgt];
    float cntr = 0.f;
    for (int i = t; i < OV; i += 256) {
        float v = lp0[i] + lp1[i];
        if (v > lt || (v == lt && i < tgt)) cntr += 1.f;
    }
    #pragma unroll
    for (int off = 32; off > 0; off >>= 1) cntr += __shfl_xor(cntr, off);
    if ((t & 63) == 0) red[t >> 6] = cntr;
    __syncthreads();
    cntr = red[0] + red[1] + red[2] + red[3];

    if (t == 0) {
        float ce = -(lt - lmax - logf(lsum));
        float inc = (tgt != EOS_TOK) ? 1.f : 0.f;
        float corr = (cntr < 2.5f) ? 1.f : 0.f;
        atomicAdd(&accum[0], ce);
        atomicAdd(&accum[1], 1.f);
        atomicAdd(&accum[2], corr * inc);
        atomicAdd(&accum[3], inc);
    }
}

// ---------------- duration head ----------------
__global__ __launch_bounds__(256) void dur1_kernel(
    const float* __restrict__ hbuf, const int* __restrict__ y1_lens,
    const float* __restrict__ dW1, const float* __restrict__ db1,
    float* __restrict__ h1buf)
{
    __shared__ float cls[DMODEL];
    int g = blockIdx.x;
    int b = g >> 3, c = g & 7;
    int t = threadIdx.x;
    const float* cp = hbuf + (size_t)(b * SEQ + XL + 1 + y1_lens[b]) * DMODEL;
    cls[t] = cp[t]; cls[t + 256] = cp[t + 256];
    __syncthreads();
    int row = c * 32 + (t >> 3);
    int ln = t & 7;
    const float* w = dW1 + (size_t)row * DMODEL + ln * 64;
    const float* cv = cls + ln * 64;
    float acc = 0.f;
    #pragma unroll 8
    for (int k = 0; k < 64; ++k) acc = fmaf(cv[k], w[k], acc);
    acc += __shfl_xor(acc, 1); acc += __shfl_xor(acc, 2); acc += __shfl_xor(acc, 4);
    if (ln == 0) h1buf[b * 256 + row] = fmaxf(acc + db1[row], 0.f);
}

__global__ __launch_bounds__(256) void dur2_kernel(
    const float* __restrict__ h1buf,
    const float* __restrict__ dW2, const float* __restrict__ db2,
    const float* __restrict__ dW3, const float* __restrict__ db3,
    float* __restrict__ preds)
{
    __shared__ float h1s[256];
    __shared__ float h2s[128];
    int b = blockIdx.x;
    int t = threadIdx.x;
    h1s[t] = h1buf[b * 256 + t];
    __syncthreads();
    if (t < 128) {
        float acc = db2[t];
        const float* w = dW2 + (size_t)t * 256;
        for (int k = 0; k < 256; ++k) acc = fmaf(h1s[k], w[k], acc);
        h2s[t] = fmaxf(acc, 0.f);
    }
    __syncthreads();
    if (t < 64) {
        float v = h2s[t] * dW3[t] + h2s[t + 64] * dW3[t + 64];
        #pragma unroll
        for (int off = 32; off > 0; off >>= 1) v += __shfl_xor(v, off);
        if (t == 0) preds[b] = v + db3[0];
    }
}

__global__ __launch_bounds__(64) void final_kernel(
    const float* __restrict__ accum, const float* __restrict__ preds,
    const int* __restrict__ y2_lens, const int* __restrict__ x2_lens,
    float* __restrict__ out)
{
    if (threadIdx.x == 0) {
        float dl = 0.f;
        for (int b = 0; b < BATCH; ++b) {
            float tgt = (float)y2_lens[b] / (float)x2_lens[b];
            float e = preds[b] - tgt;
            float ae = fabsf(e);
            dl += (ae <= 1.f) ? 0.5f * e * e : (ae - 0.5f);
        }
        dl *= (1.f / BATCH);
        float token_loss = accum[0] / accum[1];
        float acc_v = accum[2] / fmaxf(accum[3], 1.f);
        out[0] = token_loss + dl;
        out[1] = acc_v;
    }
}

// ---------------- orchestration ----------------
extern "C" void kernel_launch(void* const* d_in, const int* in_sizes, int n_in,
                              void* d_out, int out_size, void* d_ws, size_t ws_size,
                              hipStream_t stream)
{
    const int*   x           = (const int*)d_in[0];
    const int*   x1_lens     = (const int*)d_in[1];
    const int*   x2_lens     = (const int*)d_in[2];
    const int*   y           = (const int*)d_in[3];
    const int*   y1_lens     = (const int*)d_in[4];
    const int*   y2_lens     = (const int*)d_in[5];
    const int*   y_mask      = (const int*)d_in[6];
    const float* emo_feature = (const float*)d_in[7];
    const float* text_emb    = (const float*)d_in[8];
    const float* audio_emb   = (const float*)d_in[9];
    const float* type_emb    = (const float*)d_in[10];
    const float* emo_W       = (const float*)d_in[11];
    const float* emo_b       = (const float*)d_in[12];
    const float* alpha_text  = (const float*)d_in[13];
    const float* alpha_audio = (const float*)d_in[14];
    const float* Wqkv        = (const float*)d_in[15];
    const float* bqkv        = (const float*)d_in[16];
    const float* Wo          = (const float*)d_in[17];
    const float* bo          = (const float*)d_in[18];
    const float* ln1_g       = (const float*)d_in[19];
    const float* ln1_b       = (const float*)d_in[20];
    const float* ln2_g       = (const float*)d_in[21];
    const float* ln2_b       = (const float*)d_in[22];
    const float* W1          = (const float*)d_in[23];
    const float* b1          = (const float*)d_in[24];
    const float* W2          = (const float*)d_in[25];
    const float* b2          = (const float*)d_in[26];
    const float* predict_W   = (const float*)d_in[27];
    const float* dW1         = (const float*)d_in[28];
    const float* db1         = (const float*)d_in[29];
    const float* dW2         = (const float*)d_in[30];
    const float* db2         = (const float*)d_in[31];
    const float* dW3         = (const float*)d_in[32];
    const float* db3         = (const float*)d_in[33];

    const int M = BATCH * SEQ;                       // 4612
    char* p = (char*)d_ws;
    float* hbuf   = (float*)p; p += 9445376;         // M*512*4
    float* delta  = (float*)p; p += 9445376;
    char*  uni    = p;         p += 18909440;        // max(ff1_bf, logits partial0)
    u16*   hbuf_bf = (u16*)p;  p += 4722688;
    u16*   qkv_bf  = (u16*)p;  p += 14168064;        // also split-K partial region
    u16*   obuf_bf = (u16*)p;  p += 4722688;         // contiguous after qkv_bf
    u16*   wbf     = (u16*)p;  p += 19923968;
    u16*   cbuf    = (u16*)p;  p += (size_t)CCAP * DMODEL * 2;
    u16*   vtbuf   = (u16*)p;  p += (size_t)32 * 64 * SEQP * 2;   // 4.98MB V^T
    u16*   ff1_bf  = (u16*)uni;

    float* partA = (float*)qkv_bf;
    float* partB = (float*)((char*)qkv_bf + 9445376);
    float* lg0   = (float*)uni;
    float* lg1   = (float*)qkv_bf;

    float* accum  = delta;
    int*   cnt    = (int*)(delta + 4);
    float* preds  = delta + 8;
    int*   cmap   = (int*)(delta + 16);
    int*   ctgt   = cmap + CCAP;
    float* h1buf  = (float*)(ctgt + CCAP);

    u16* wq_bf = wbf;                                // 3*1536*512
    u16* wo_bf = wq_bf + 2359296;                    // 3*512*512
    u16* w1_bf = wo_bf + 786432;                     // 3*2048*512
    u16* w2_bf = w1_bf + 3145728;                    // 3*512*2048
    u16* wp_bf = w2_bf + 3145728;                    // 1025*512

    cvt5_kernel<<<1024, 256, 0, stream>>>(
        Wqkv, wq_bf, 2359296 / 4,
        Wo, wo_bf, 786432 / 4,
        W1, w1_bf, 3145728 / 4,
        W2, w2_bf, 3145728 / 4,
        predict_W, wp_bf, 524800 / 4);

    emo_kernel<<<32, 256, 0, stream>>>(emo_feature, emo_W, emo_b, type_emb, hbuf, hbuf_bf);
    build_h_kernel<<<M / 4, 256, 0, stream>>>(
        x, y, y_mask, text_emb, audio_emb, type_emb,
        alpha_text, alpha_audio, hbuf, hbuf_bf);

    const int MG = (M + 127) / 128;   // 37
    for (int l = 0; l < NLAYER; ++l) {
        gemm_bf16_kernel<<<dim3(12, MG), 256, 0, stream>>>(
            hbuf_bf, wq_bf + (size_t)l * 1536 * 512, bqkv + l * 1536,
            nullptr, qkv_bf, M, 1536, 512, 0);
        vtrans_kernel<<<dim3(19, 32), 256, 0, stream>>>(qkv_bf, vtbuf);
        attn_mfma_kernel<<<dim3((SEQ + QBLK - 1) / QBLK, BATCH * NH), 512, 0, stream>>>(
            qkv_bf, vtbuf, x1_lens, x2_lens, y1_lens, y2_lens, y_mask, obuf_bf);
        gemm_bf16_splitk_kernel<<<dim3(4, MG, 2), 256, 0, stream>>>(
            obuf_bf, wo_bf + (size_t)l * 512 * 512,
            delta, partA, nullptr, M, 512, 512, 256);
        add_ln_kernel<<<M / 4, 256, 0, stream>>>(hbuf, hbuf_bf,
            delta, partA, nullptr, bo + l * 512,
            ln1_g + l * DMODEL, ln1_b + l * DMODEL);
        gemm_bf16_kernel<<<dim3(16, MG), 256, 0, stream>>>(
            hbuf_bf, w1_bf + (size_t)l * 2048 * 512, b1 + l * 2048,
            nullptr, ff1_bf, M, 2048, 512, 1);
        gemm_bf16_splitk_kernel<<<dim3(4, MG, 3), 256, 0, stream>>>(
            ff1_bf, w2_bf + (size_t)l * 512 * 2048,
            delta, partA, partB, M, 512, 2048, 768);
        add_ln_kernel<<<M / 4, 256, 0, stream>>>(hbuf, hbuf_bf,
            delta, partA, partB, b2 + l * 512,
            ln2_g + l * DMODEL, ln2_b + l * DMODEL);
    }

    init_accum_kernel<<<1, 64, 0, stream>>>(accum);
    compact_kernel<<<(BATCH * YL) / 256, 256, 0, stream>>>(y_mask, cnt, cmap);
    copy_rows_kernel<<<CCAP, 256, 0, stream>>>(cnt, cmap, hbuf_bf, y, cbuf, ctgt);
    gemm_bf16_splitk_dynm_kernel<<<dim3((OV + 127) / 128, CCAP / 128, 2), 256, 0, stream>>>(
        cbuf, wp_bf, cnt, lg0, lg1, OV, 512, 256);
    ce_kernel<<<CCAP, 256, 0, stream>>>(cnt, lg0, lg1, ctgt, accum);

    dur1_kernel<<<32, 256, 0, stream>>>(hbuf, y1_lens, dW1, db1, h1buf);
    dur2_kernel<<<4, 256, 0, stream>>>(h1buf, dW2, db2, dW3, db3, preds);
    final_kernel<<<1, 64, 0, stream>>>(accum, preds, y2_lens, x2_lens, (float*)d_out);
}

// Round 10
// 598.548 us; speedup vs baseline: 1.2132x; 1.2132x over previous
//
#include <hip/hip_runtime.h>
#include <hip/hip_bf16.h>
#include <math.h>

#define BATCH 4
#define XL 128
#define YL 1024
#define DMODEL 512
#define NH 8
#define NLAYER 3
#define DFF 2048
#define MASK_ID 1024
#define EOS_TOK 1024
#define HD 64
#define SEQ 1153          // XL + 1 + YL
#define OV 1025
#define NEGBIG (-1e9f)
#define QBLK 128
#define CCAP 2432         // max compacted masked rows
#define NROWS 36896       // BATCH*SEQ*NH

typedef unsigned short u16;
typedef unsigned int u32;
typedef short short8 __attribute__((ext_vector_type(8)));
typedef float f32x4 __attribute__((ext_vector_type(4)));

__device__ __forceinline__ u16 f2bf(float f) {
    union { float f; unsigned u; } v; v.f = f;
    unsigned r = v.u + 0x7fffu + ((v.u >> 16) & 1u);   // RNE
    return (u16)(r >> 16);
}
__device__ __forceinline__ float bf2f(u16 b) {
    union { unsigned u; float f; } v; v.u = ((unsigned)b) << 16;
    return v.f;
}

// ---------------- fused f32 -> bf16 convert for all 5 weight tensors ----------------
__global__ __launch_bounds__(256) void cvt5_kernel(
    const float* __restrict__ s0, u16* __restrict__ d0, int n0,
    const float* __restrict__ s1, u16* __restrict__ d1, int n1,
    const float* __restrict__ s2, u16* __restrict__ d2, int n2,
    const float* __restrict__ s3, u16* __restrict__ d3, int n3,
    const float* __restrict__ s4, u16* __restrict__ d4, int n4)
{
    int c0 = n0, c1 = c0 + n1, c2 = c1 + n2, c3 = c2 + n3, c4 = c3 + n4;
    for (int i = blockIdx.x * 256 + threadIdx.x; i < c4; i += gridDim.x * 256) {
        const float* s; u16* d; int j;
        if (i < c0)      { s = s0; d = d0; j = i; }
        else if (i < c1) { s = s1; d = d1; j = i - c0; }
        else if (i < c2) { s = s2; d = d2; j = i - c1; }
        else if (i < c3) { s = s3; d = d3; j = i - c2; }
        else             { s = s4; d = d4; j = i - c3; }
        float4 v = ((const float4*)s)[j];
        ushort4 o;
        o.x = f2bf(v.x); o.y = f2bf(v.y); o.z = f2bf(v.z); o.w = f2bf(v.w);
        ((ushort4*)d)[j] = o;
    }
}

// ---------------- emo rows ----------------
__global__ __launch_bounds__(256) void emo_kernel(
    const float* __restrict__ emo_feature, const float* __restrict__ emo_W,
    const float* __restrict__ emo_b, const float* __restrict__ type_emb,
    float* __restrict__ hbuf, u16* __restrict__ hbuf_bf)
{
    int b = blockIdx.x >> 3, c = blockIdx.x & 7;
    int t = threadIdx.x;
    int osub = t >> 2, ln = t & 3;
    int d = c * 64 + osub;
    const float* f = emo_feature + b * 768 + ln * 192;
    const float* w = emo_W + (size_t)d * 768 + ln * 192;
    float acc = 0.f;
    #pragma unroll 4
    for (int k = 0; k < 192; ++k) acc = fmaf(f[k], w[k], acc);
    acc += __shfl_xor(acc, 1);
    acc += __shfl_xor(acc, 2);
    if (ln == 0) {
        float v = acc + emo_b[d] + type_emb[DMODEL + d];
        hbuf[(size_t)(b * SEQ + XL) * DMODEL + d] = v;
        hbuf_bf[(size_t)(b * SEQ + XL) * DMODEL + d] = f2bf(v);
    }
}

// ---------------- build h_input (x & y rows), wave-per-row ----------------
__global__ __launch_bounds__(256) void build_h_kernel(
    const int* __restrict__ x, const int* __restrict__ y, const int* __restrict__ y_mask,
    const float* __restrict__ text_emb, const float* __restrict__ audio_emb,
    const float* __restrict__ type_emb,
    const float* __restrict__ alpha_text, const float* __restrict__ alpha_audio,
    float* __restrict__ hbuf, u16* __restrict__ hbuf_bf)
{
    int row = blockIdx.x * 4 + (threadIdx.x >> 6);
    int l = threadIdx.x & 63;
    int b = row / SEQ, s = row % SEQ;
    if (s == XL) return;
    int d0 = l * 8;

    const float* emb; const float* te; float alpha; int pos;
    if (s < XL) {
        int tok = x[b * XL + s];
        emb = text_emb + (size_t)tok * DMODEL;
        te = type_emb; alpha = alpha_text[0]; pos = s;
    } else {
        int r = s - XL - 1;
        int tok = y_mask[b * YL + r] ? MASK_ID : y[b * YL + r];
        emb = audio_emb + (size_t)tok * DMODEL;
        te = type_emb + 2 * DMODEL; alpha = alpha_audio[0]; pos = r;
    }

    float4 e0 = *(const float4*)(emb + d0);
    float4 e1 = *(const float4*)(emb + d0 + 4);
    float4 t0 = *(const float4*)(te + d0);
    float4 t1 = *(const float4*)(te + d0 + 4);
    float v[8] = {e0.x + t0.x, e0.y + t0.y, e0.z + t0.z, e0.w + t0.w,
                  e1.x + t1.x, e1.y + t1.y, e1.z + t1.z, e1.w + t1.w};
    float fp = (float)pos;
    #pragma unroll
    for (int p = 0; p < 4; ++p) {
        int d = d0 + 2 * p;
        float div = __expf((float)d * (-9.210340371976184f / (float)DMODEL));
        float sn, cs;
        __sincosf(fp * div, &sn, &cs);
        v[2 * p]     += alpha * sn;
        v[2 * p + 1] += alpha * cs;
    }

    float* hp = hbuf + (size_t)row * DMODEL + d0;
    *(float4*)hp       = make_float4(v[0], v[1], v[2], v[3]);
    *(float4*)(hp + 4) = make_float4(v[4], v[5], v[6], v[7]);
    short8 sv;
    #pragma unroll
    for (int e = 0; e < 8; ++e) sv[e] = (short)f2bf(v[e]);
    *(short8*)(hbuf_bf + (size_t)row * DMODEL + d0) = sv;
}

// ---------------- bf16 MFMA NT GEMM (full-K) ----------
__global__ __launch_bounds__(256) void gemm_bf16_kernel(
    const u16* __restrict__ A, const u16* __restrict__ Bw,
    const float* __restrict__ bias,
    float* __restrict__ Cf, u16* __restrict__ Cb,
    int M, int N, int K, int relu)
{
    __shared__ u16 As[128 * 32];
    __shared__ u16 Bs[128 * 32];
    int tid = threadIdx.x;
    int w = tid >> 6, l = tid & 63;
    int m0 = blockIdx.y * 128, n0 = blockIdx.x * 128;
    int wm = (w >> 1) * 64, wn = (w & 1) * 64;

    f32x4 acc[4][4];
    #pragma unroll
    for (int i = 0; i < 4; ++i)
        #pragma unroll
        for (int j = 0; j < 4; ++j) acc[i][j] = (f32x4){0.f, 0.f, 0.f, 0.f};

    int srow0 = (w << 5) + (l >> 2);
    int skp = (l & 3) << 3;

    for (int k0 = 0; k0 < K; k0 += 32) {
        #pragma unroll
        for (int c = 0; c < 2; ++c) {
            int row = srow0 + c * 16;
            int am = m0 + row; if (am >= M) am = M - 1;
            int bn = n0 + row; if (bn >= N) bn = N - 1;
            __builtin_amdgcn_global_load_lds(
                (const __attribute__((address_space(1))) void*)(A + (size_t)am * K + k0 + skp),
                (__attribute__((address_space(3))) void*)(As + ((w * 2 + c) << 9)), 16, 0, 0);
            __builtin_amdgcn_global_load_lds(
                (const __attribute__((address_space(1))) void*)(Bw + (size_t)bn * K + k0 + skp),
                (__attribute__((address_space(3))) void*)(Bs + ((w * 2 + c) << 9)), 16, 0, 0);
        }
        __syncthreads();
        short8 af[4], bfr[4];
        #pragma unroll
        for (int i = 0; i < 4; ++i) {
            af[i]  = *(const short8*)(As + (wm + i * 16 + (l & 15)) * 32 + ((l >> 4) << 3));
            bfr[i] = *(const short8*)(Bs + (wn + i * 16 + (l & 15)) * 32 + ((l >> 4) << 3));
        }
        #pragma unroll
        for (int i = 0; i < 4; ++i)
            #pragma unroll
            for (int j = 0; j < 4; ++j)
                acc[i][j] = __builtin_amdgcn_mfma_f32_16x16x32_bf16(af[i], bfr[j], acc[i][j], 0, 0, 0);
        __syncthreads();
    }

    #pragma unroll
    for (int i = 0; i < 4; ++i) {
        #pragma unroll
        for (int j = 0; j < 4; ++j) {
            #pragma unroll
            for (int jj = 0; jj < 4; ++jj) {
                int row = m0 + wm + i * 16 + ((l >> 4) << 2) + jj;
                int col = n0 + wn + j * 16 + (l & 15);
                if (row < M && col < N) {
                    float v = acc[i][j][jj];
                    if (bias) v += bias[col];
                    if (relu) v = fmaxf(v, 0.f);
                    if (Cf) Cf[(size_t)row * N + col] = v;
                    if (Cb) Cb[(size_t)row * N + col] = f2bf(v);
                }
            }
        }
    }
}

// ---- split-K variant ----
__global__ __launch_bounds__(256) void gemm_bf16_splitk_kernel(
    const u16* __restrict__ A, const u16* __restrict__ Bw,
    float* __restrict__ P0, float* __restrict__ P1, float* __restrict__ P2,
    int M, int N, int K, int klen)
{
    __shared__ u16 As[128 * 32];
    __shared__ u16 Bs[128 * 32];
    int tid = threadIdx.x;
    int w = tid >> 6, l = tid & 63;
    int z = blockIdx.z;
    float* Cp = (z == 0) ? P0 : (z == 1) ? P1 : P2;
    int kbeg = z * klen;
    int kend = min(kbeg + klen, K);
    int m0 = blockIdx.y * 128, n0 = blockIdx.x * 128;
    int wm = (w >> 1) * 64, wn = (w & 1) * 64;

    f32x4 acc[4][4];
    #pragma unroll
    for (int i = 0; i < 4; ++i)
        #pragma unroll
        for (int j = 0; j < 4; ++j) acc[i][j] = (f32x4){0.f, 0.f, 0.f, 0.f};

    int srow0 = (w << 5) + (l >> 2);
    int skp = (l & 3) << 3;

    for (int k0 = kbeg; k0 < kend; k0 += 32) {
        #pragma unroll
        for (int c = 0; c < 2; ++c) {
            int row = srow0 + c * 16;
            int am = m0 + row; if (am >= M) am = M - 1;
            int bn = n0 + row; if (bn >= N) bn = N - 1;
            __builtin_amdgcn_global_load_lds(
                (const __attribute__((address_space(1))) void*)(A + (size_t)am * K + k0 + skp),
                (__attribute__((address_space(3))) void*)(As + ((w * 2 + c) << 9)), 16, 0, 0);
            __builtin_amdgcn_global_load_lds(
                (const __attribute__((address_space(1))) void*)(Bw + (size_t)bn * K + k0 + skp),
                (__attribute__((address_space(3))) void*)(Bs + ((w * 2 + c) << 9)), 16, 0, 0);
        }
        __syncthreads();
        short8 af[4], bfr[4];
        #pragma unroll
        for (int i = 0; i < 4; ++i) {
            af[i]  = *(const short8*)(As + (wm + i * 16 + (l & 15)) * 32 + ((l >> 4) << 3));
            bfr[i] = *(const short8*)(Bs + (wn + i * 16 + (l & 15)) * 32 + ((l >> 4) << 3));
        }
        #pragma unroll
        for (int i = 0; i < 4; ++i)
            #pragma unroll
            for (int j = 0; j < 4; ++j)
                acc[i][j] = __builtin_amdgcn_mfma_f32_16x16x32_bf16(af[i], bfr[j], acc[i][j], 0, 0, 0);
        __syncthreads();
    }

    #pragma unroll
    for (int i = 0; i < 4; ++i) {
        #pragma unroll
        for (int j = 0; j < 4; ++j) {
            #pragma unroll
            for (int jj = 0; jj < 4; ++jj) {
                int row = m0 + wm + i * 16 + ((l >> 4) << 2) + jj;
                int col = n0 + wn + j * 16 + (l & 15);
                if (row < M && col < N)
                    Cp[(size_t)row * N + col] = acc[i][j][jj];
            }
        }
    }
}

// ---- split-K + dynamic-M (logits) ----
__global__ __launch_bounds__(256) void gemm_bf16_splitk_dynm_kernel(
    const u16* __restrict__ A, const u16* __restrict__ Bw,
    const int* __restrict__ Mp,
    float* __restrict__ P0, float* __restrict__ P1,
    int N, int K, int klen)
{
    int M = *Mp;
    int m0 = blockIdx.y * 128;
    if (m0 >= M) return;
    __shared__ u16 As[128 * 32];
    __shared__ u16 Bs[128 * 32];
    int tid = threadIdx.x;
    int w = tid >> 6, l = tid & 63;
    int z = blockIdx.z;
    float* Cp = (z == 0) ? P0 : P1;
    int kbeg = z * klen;
    int kend = min(kbeg + klen, K);
    int n0 = blockIdx.x * 128;
    int wm = (w >> 1) * 64, wn = (w & 1) * 64;

    f32x4 acc[4][4];
    #pragma unroll
    for (int i = 0; i < 4; ++i)
        #pragma unroll
        for (int j = 0; j < 4; ++j) acc[i][j] = (f32x4){0.f, 0.f, 0.f, 0.f};

    int srow0 = (w << 5) + (l >> 2);
    int skp = (l & 3) << 3;

    for (int k0 = kbeg; k0 < kend; k0 += 32) {
        #pragma unroll
        for (int c = 0; c < 2; ++c) {
            int row = srow0 + c * 16;
            int am = m0 + row; if (am >= M) am = M - 1;
            int bn = n0 + row; if (bn >= N) bn = N - 1;
            __builtin_amdgcn_global_load_lds(
                (const __attribute__((address_space(1))) void*)(A + (size_t)am * K + k0 + skp),
                (__attribute__((address_space(3))) void*)(As + ((w * 2 + c) << 9)), 16, 0, 0);
            __builtin_amdgcn_global_load_lds(
                (const __attribute__((address_space(1))) void*)(Bw + (size_t)bn * K + k0 + skp),
                (__attribute__((address_space(3))) void*)(Bs + ((w * 2 + c) << 9)), 16, 0, 0);
        }
        __syncthreads();
        short8 af[4], bfr[4];
        #pragma unroll
        for (int i = 0; i < 4; ++i) {
            af[i]  = *(const short8*)(As + (wm + i * 16 + (l & 15)) * 32 + ((l >> 4) << 3));
            bfr[i] = *(const short8*)(Bs + (wn + i * 16 + (l & 15)) * 32 + ((l >> 4) << 3));
        }
        #pragma unroll
        for (int i = 0; i < 4; ++i)
            #pragma unroll
            for (int j = 0; j < 4; ++j)
                acc[i][j] = __builtin_amdgcn_mfma_f32_16x16x32_bf16(af[i], bfr[j], acc[i][j], 0, 0, 0);
        __syncthreads();
    }

    #pragma unroll
    for (int i = 0; i < 4; ++i) {
        #pragma unroll
        for (int j = 0; j < 4; ++j) {
            #pragma unroll
            for (int jj = 0; jj < 4; ++jj) {
                int row = m0 + wm + i * 16 + ((l >> 4) << 2) + jj;
                int col = n0 + wn + j * 16 + (l & 15);
                if (row < M && col < N)
                    Cp[(size_t)row * N + col] = acc[i][j][jj];
            }
        }
    }
}

// ============== MFMA flash attention (R7 structure) + K-SPLIT (flash-decoding) =======
// grid (10, 32, 2), 512 thr = 8 waves; wave w owns q rows [q0+16w, q0+16w+16).
// blockIdx.z halves the k-tile range; writes unnormalized O~ (f32) + m,l per row.
__global__ __launch_bounds__(512) void attn_mfma_kernel(
    const u16* __restrict__ qkv,
    const int* __restrict__ x1_lens, const int* __restrict__ x2_lens,
    const int* __restrict__ y1_lens, const int* __restrict__ y2_lens,
    const int* __restrict__ y_mask,
    float* __restrict__ opart, float* __restrict__ ml)
{
    __shared__ u16 Ks[64 * 64];                 // [k][d] XOR-swizzled
    __shared__ u16 Vt[64 * 64];                 // [d][k] XOR-swizzled
    __shared__ unsigned long long Bits[7][19];  // per-rowtype per-tile allow bitmap

    int tid = threadIdx.x;
    int w = tid >> 6, l = tid & 63;
    int g = l >> 4;                 // lane group 0..3
    int q = l & 15;                 // q-row within wave tile
    int bh = blockIdx.y;
    int b = bh >> 3, h = bh & 7;
    int q0 = blockIdx.x * QBLK;
    int z = blockIdx.z;

    int x1 = x1_lens[b], xlen = x1 + 1 + x2_lens[b];
    int y1 = y1_lens[b], ylen = y1 + 1 + y2_lens[b];

    // ---- block-level kmax over alive rows (dead blocks process 1 masked tile) ----
    int kmax = -1;
    if (q0 < XL) kmax = max(kmax, xlen - 1);
    if (XL >= q0 && XL < q0 + QBLK) kmax = max(kmax, XL);
    {
        int ry0 = max(0, q0 - XL - 1);
        int ry1 = min(YL - 1, q0 + QBLK - 2 - XL);
        if (ry0 <= ry1) {
            if (ry0 <= y1 - 1) kmax = max(kmax, XL + y1);
            if (y1 >= ry0 && y1 <= ry1) kmax = max(kmax, XL + y1 + 1);
            int a = max(ry0, y1 + 1), bb = min(ry1, ylen - 1);
            if (a <= bb) kmax = max(kmax, XL + ylen);
        }
    }
    if (kmax < 0) kmax = 0;          // finite uniform output for dead rows (no NaN downstream)
    int NKT = (kmax >> 6) + 1;
    int half = (NKT + 1) >> 1;
    int kbeg = z ? half : 0;
    int kend = z ? NKT : half;

    // ---- allow bitmaps via wave ballot ----
    for (int pp = w; pp < 7 * 19; pp += 8) {
        int ty = pp / 19, tile = pp - ty * 19;
        int c = tile * 64 + l;
        bool allow = false;
        if (c < SEQ && ty < 6) {
            bool a2c = (c == XL), ygt = (c > XL);
            if (ty == 0) allow = (c < x1);
            else if (ty == 1) allow = (c >= x1) && (c < xlen);
            else if (ty == 2) allow = a2c;
            else if (ty == 3) allow = (c < x1) || (ygt && c <= XL + y1);
            else if (ty == 4) allow = (c < xlen) || a2c || (ygt && c <= XL + y1 + 1);
            else {
                int ym = ygt ? y_mask[b * YL + c - XL - 1] : 0;
                allow = (((c < xlen) || a2c || (ygt && c <= XL + ylen)) && !ym);
            }
        }
        unsigned long long mk = __ballot(allow);
        if (l == 0) Bits[ty][tile] = mk;
    }

    // ---- Q fragment (q = l&15), scale 1/8 folded in ----
    int qr = q0 + w * 16 + q;
    int qrc = min(qr, SEQ - 1);
    short8 qf0, qf1;
    {
        const u16* qp = qkv + (size_t)(b * SEQ + qrc) * 1536 + h * 64 + (g << 3);
        short8 r0 = *(const short8*)qp;
        short8 r1 = *(const short8*)(qp + 32);
        #pragma unroll
        for (int e = 0; e < 8; ++e) {
            qf0[e] = (short)f2bf(bf2f((u16)r0[e]) * 0.125f);
            qf1[e] = (short)f2bf(bf2f((u16)r1[e]) * 0.125f);
        }
    }

    // ---- row type of this lane's q ----
    int rt;
    {
        if (qr >= SEQ) rt = 6;
        else if (qr < XL) rt = (qr < x1) ? 0 : 1;
        else if (qr == XL) rt = 2;
        else {
            int ry = qr - XL - 1;
            rt = (ry < y1) ? 3 : (ry == y1) ? 4 : (ry < ylen) ? 5 : 6;
        }
    }

    f32x4 oacc[4];
    #pragma unroll
    for (int db = 0; db < 4; ++db) oacc[db] = (f32x4){0.f, 0.f, 0.f, 0.f};
    float mrun = -INFINITY, lrun = 0.f;

    int srcA = q + ((g & 1) << 5);
    int srcB = srcA + 16;
    bool hi = (g >> 1) & 1;

    for (int kt = kbeg; kt < kend; ++kt) {
        __syncthreads();
        {   // stage K rows: 512 thr, one b128 each
            int r = tid >> 3, d0k = (tid & 7) << 3;
            int krc = min(kt * 64 + r, SEQ - 1);
            short8 ka = *(const short8*)(qkv + (size_t)(b * SEQ + krc) * 1536 + 512 + h * 64 + d0k);
            *(short8*)&Ks[r * 64 + (d0k ^ ((r & 7) << 3))] = ka;
        }
        {   // stage V^T: 2 k-rows x 4 d per thread, paired u32 writes
            int rp = tid >> 4, o = tid & 15;
            int d0v = o * 4;
            int k0r = min(kt * 64 + 2 * rp, SEQ - 1);
            int k1r = min(kt * 64 + 2 * rp + 1, SEQ - 1);
            ushort4 va = *(const ushort4*)(qkv + (size_t)(b * SEQ + k0r) * 1536 + 1024 + h * 64 + d0v);
            ushort4 vb = *(const ushort4*)(qkv + (size_t)(b * SEQ + k1r) * 1536 + 1024 + h * 64 + d0v);
            u32 pv[4] = {(u32)va.x | ((u32)vb.x << 16), (u32)va.y | ((u32)vb.y << 16),
                         (u32)va.z | ((u32)vb.z << 16), (u32)va.w | ((u32)vb.w << 16)};
            #pragma unroll
            for (int e = 0; e < 4; ++e) {
                int d = d0v + e;
                *(u32*)&Vt[d * 64 + ((2 * rp) ^ ((d & 7) << 3))] = pv[e];
            }
        }
        __syncthreads();

        // ---- QK^T swapped: sc[cb][reg] = S^T[k = 16cb+4g+reg][q] ----
        f32x4 sc[4];
        #pragma unroll
        for (int cb = 0; cb < 4; ++cb) {
            int krw = cb * 16 + q;
            int ksw = (krw & 7) << 3;
            short8 k0 = *(const short8*)&Ks[krw * 64 + ((g << 3) ^ ksw)];
            short8 k1 = *(const short8*)&Ks[krw * 64 + ((32 + (g << 3)) ^ ksw)];
            f32x4 zz = (f32x4){0.f, 0.f, 0.f, 0.f};
            zz = __builtin_amdgcn_mfma_f32_16x16x32_bf16(k0, qf0, zz, 0, 0, 0);
            sc[cb] = __builtin_amdgcn_mfma_f32_16x16x32_bf16(k1, qf1, zz, 0, 0, 0);
        }

        // ---- mask via bitmap ----
        unsigned long long mb = Bits[rt][kt];
        #pragma unroll
        for (int cb = 0; cb < 4; ++cb) {
            unsigned nib = (unsigned)(mb >> (16 * cb + 4 * g)) & 0xFu;
            #pragma unroll
            for (int r = 0; r < 4; ++r)
                sc[cb][r] = ((nib >> r) & 1u) ? sc[cb][r] : NEGBIG;
        }

        // ---- in-register online softmax (one q-row per lane) ----
        float tmax = sc[0][0];
        #pragma unroll
        for (int cb = 0; cb < 4; ++cb)
            #pragma unroll
            for (int r = 0; r < 4; ++r) tmax = fmaxf(tmax, sc[cb][r]);
        tmax = fmaxf(tmax, __shfl_xor(tmax, 16));
        tmax = fmaxf(tmax, __shfl_xor(tmax, 32));
        float newm = fmaxf(mrun, tmax);
        float corr = __expf(mrun - newm);
        float p[4][4];
        float ps = 0.f;
        #pragma unroll
        for (int cb = 0; cb < 4; ++cb)
            #pragma unroll
            for (int r = 0; r < 4; ++r) {
                p[cb][r] = __expf(sc[cb][r] - newm);
                ps += p[cb][r];
            }
        ps += __shfl_xor(ps, 16);
        ps += __shfl_xor(ps, 32);
        lrun = lrun * corr + ps;
        mrun = newm;

        // ---- rescale O (lane holds O rows 4g+r) ----
        float cr[4];
        #pragma unroll
        for (int r = 0; r < 4; ++r) cr[r] = __shfl(corr, (g << 2) + r);
        #pragma unroll
        for (int db = 0; db < 4; ++db)
            #pragma unroll
            for (int r = 0; r < 4; ++r) oacc[db][r] *= cr[r];

        // ---- pack P to bf16 pairs ----
        u32 P0[4], P1[4];
        #pragma unroll
        for (int cb = 0; cb < 4; ++cb) {
            P0[cb] = (u32)f2bf(p[cb][0]) | ((u32)f2bf(p[cb][1]) << 16);
            P1[cb] = (u32)f2bf(p[cb][2]) | ((u32)f2bf(p[cb][3]) << 16);
        }

        // ---- exchange -> A-fragments for PV ----
        union { u32 u[4]; short8 s; } f1, f2;
        {
            u32 a0 = __shfl(P0[0], srcA), a1 = __shfl(P1[0], srcA);
            u32 a2 = __shfl(P0[0], srcB), a3 = __shfl(P1[0], srcB);
            u32 b0 = __shfl(P0[1], srcA), b1 = __shfl(P1[1], srcA);
            u32 b2 = __shfl(P0[1], srcB), b3 = __shfl(P1[1], srcB);
            f1.u[0] = hi ? b0 : a0; f1.u[1] = hi ? b1 : a1;
            f1.u[2] = hi ? b2 : a2; f1.u[3] = hi ? b3 : a3;
            u32 c0 = __shfl(P0[2], srcA), c1 = __shfl(P1[2], srcA);
            u32 c2 = __shfl(P0[2], srcB), c3 = __shfl(P1[2], srcB);
            u32 d0 = __shfl(P0[3], srcA), d1 = __shfl(P1[3], srcA);
            u32 d2 = __shfl(P0[3], srcB), d3 = __shfl(P1[3], srcB);
            f2.u[0] = hi ? d0 : c0; f2.u[1] = hi ? d1 : c1;
            f2.u[2] = hi ? d2 : c2; f2.u[3] = hi ? d3 : c3;
        }

        // ---- PV: O[q=4g+r][d] += P V ----
        #pragma unroll
        for (int db = 0; db < 4; ++db) {
            int vr = db * 16 + q;
            int vsw = (vr & 7) << 3;
            short8 v0 = *(const short8*)&Vt[vr * 64 + ((g << 3) ^ vsw)];
            short8 v1 = *(const short8*)&Vt[vr * 64 + ((32 + (g << 3)) ^ vsw)];
            oacc[db] = __builtin_amdgcn_mfma_f32_16x16x32_bf16(f1.s, v0, oacc[db], 0, 0, 0);
            oacc[db] = __builtin_amdgcn_mfma_f32_16x16x32_bf16(f2.s, v1, oacc[db], 0, 0, 0);
        }
    }

    // ---- write unnormalized O~ (f32) and per-row m,l ----
    if (g == 0) {
        int row = q0 + w * 16 + q;
        if (row < SEQ) {
            int ridx = (b * SEQ + row) * 8 + h;
            ml[(size_t)(z * 2) * NROWS + ridx] = mrun;
            ml[(size_t)(z * 2 + 1) * NROWS + ridx] = lrun;
        }
    }
    float* op = opart + (size_t)z * NROWS * 64;
    #pragma unroll
    for (int db = 0; db < 4; ++db) {
        #pragma unroll
        for (int r = 0; r < 4; ++r) {
            int qrj = q0 + w * 16 + (g << 2) + r;
            if (qrj < SEQ) {
                int ridx = (b * SEQ + qrj) * 8 + h;
                op[(size_t)ridx * 64 + db * 16 + q] = oacc[db][r];
            }
        }
    }
}

// ---- merge the two k-splits: O = (w0 O0 + w1 O1) / (w0 l0 + w1 l1) ----
__global__ __launch_bounds__(256) void attn_merge_kernel(
    const float* __restrict__ opart, const float* __restrict__ ml,
    u16* __restrict__ obuf)
{
    int r = blockIdx.x * 4 + (threadIdx.x >> 6);   // row index (b*SEQ+s)*8+h
    int d = threadIdx.x & 63;
    float m0 = ml[r], l0 = ml[NROWS + r];
    float m1 = ml[2 * NROWS + r], l1 = ml[3 * NROWS + r];
    float M = fmaxf(m0, m1);
    float w0 = __expf(m0 - M), w1 = __expf(m1 - M);
    float denom = w0 * l0 + w1 * l1;
    float o0 = opart[(size_t)r * 64 + d];
    float o1 = opart[(size_t)(NROWS + r) * 64 + d];
    float v = (w0 * o0 + w1 * o1) / denom;
    int bs = r >> 3, h = r & 7;
    obuf[(size_t)bs * DMODEL + h * 64 + d] = f2bf(v);
}

// ------- residual add + fused split-K reduce (+bias) + LayerNorm, wave-per-row -------
__global__ __launch_bounds__(256) void add_ln_kernel(
    float* __restrict__ hbuf, u16* __restrict__ hbuf_bf,
    const float* __restrict__ p0, const float* __restrict__ p1,
    const float* __restrict__ p2, const float* __restrict__ bias,
    const float* __restrict__ g, const float* __restrict__ beta)
{
    int row = blockIdx.x * 4 + (threadIdx.x >> 6);
    int l = threadIdx.x & 63;
    int d0 = l * 8;
    size_t off = (size_t)row * DMODEL + d0;
    float* hp = hbuf + off;
    float4 a0 = *(const float4*)hp, a1 = *(const float4*)(hp + 4);
    float4 q0 = *(const float4*)(p0 + off), q1 = *(const float4*)(p0 + off + 4);
    float v[8] = {a0.x + q0.x, a0.y + q0.y, a0.z + q0.z, a0.w + q0.w,
                  a1.x + q1.x, a1.y + q1.y, a1.z + q1.z, a1.w + q1.w};
    if (p1) {
        float4 r0 = *(const float4*)(p1 + off), r1 = *(const float4*)(p1 + off + 4);
        v[0] += r0.x; v[1] += r0.y; v[2] += r0.z; v[3] += r0.w;
        v[4] += r1.x; v[5] += r1.y; v[6] += r1.z; v[7] += r1.w;
    }
    if (p2) {
        float4 r0 = *(const float4*)(p2 + off), r1 = *(const float4*)(p2 + off + 4);
        v[0] += r0.x; v[1] += r0.y; v[2] += r0.z; v[3] += r0.w;
        v[4] += r1.x; v[5] += r1.y; v[6] += r1.z; v[7] += r1.w;
    }
    {
        float4 b0 = *(const float4*)(bias + d0), b1 = *(const float4*)(bias + d0 + 4);
        v[0] += b0.x; v[1] += b0.y; v[2] += b0.z; v[3] += b0.w;
        v[4] += b1.x; v[5] += b1.y; v[6] += b1.z; v[7] += b1.w;
    }
    float s = 0.f;
    #pragma unroll
    for (int e = 0; e < 8; ++e) s += v[e];
    #pragma unroll
    for (int off2 = 32; off2 > 0; off2 >>= 1) s += __shfl_xor(s, off2);
    float mu = s * (1.f / DMODEL);
    float sq = 0.f;
    #pragma unroll
    for (int e = 0; e < 8; ++e) { v[e] -= mu; sq += v[e] * v[e]; }
    #pragma unroll
    for (int off2 = 32; off2 > 0; off2 >>= 1) sq += __shfl_xor(sq, off2);
    float inv = 1.f / sqrtf(sq * (1.f / DMODEL) + 1e-5f);
    float4 g0 = *(const float4*)(g + d0), g1 = *(const float4*)(g + d0 + 4);
    float4 be0 = *(const float4*)(beta + d0), be1 = *(const float4*)(beta + d0 + 4);
    float o[8];
    o[0] = v[0] * inv * g0.x + be0.x; o[1] = v[1] * inv * g0.y + be0.y;
    o[2] = v[2] * inv * g0.z + be0.z; o[3] = v[3] * inv * g0.w + be0.w;
    o[4] = v[4] * inv * g1.x + be1.x; o[5] = v[5] * inv * g1.y + be1.y;
    o[6] = v[6] * inv * g1.z + be1.z; o[7] = v[7] * inv * g1.w + be1.w;
    *(float4*)hp       = make_float4(o[0], o[1], o[2], o[3]);
    *(float4*)(hp + 4) = make_float4(o[4], o[5], o[6], o[7]);
    short8 sv;
    #pragma unroll
    for (int e = 0; e < 8; ++e) sv[e] = (short)f2bf(o[e]);
    *(short8*)(hbuf_bf + off) = sv;
}

// ---------------- compaction of masked rows ----------------
__global__ __launch_bounds__(256) void init_accum_kernel(float* accum) {
    if (threadIdx.x < 8) accum[threadIdx.x] = 0.f;
}

__global__ __launch_bounds__(256) void compact_kernel(
    const int* __restrict__ y_mask, int* __restrict__ cnt, int* __restrict__ cmap)
{
    int i = blockIdx.x * 256 + threadIdx.x;
    if (i < BATCH * YL && y_mask[i]) {
        int pos = atomicAdd(cnt, 1);
        cmap[pos] = i;
    }
}

__global__ __launch_bounds__(256) void copy_rows_kernel(
    const int* __restrict__ cnt, const int* __restrict__ cmap,
    const u16* __restrict__ hbuf_bf, const int* __restrict__ y,
    u16* __restrict__ cbuf, int* __restrict__ ctgt)
{
    int i = blockIdx.x;
    if (i >= *cnt) return;
    int g = cmap[i];
    int b = g >> 10, r = g & 1023;
    const u16* src = hbuf_bf + (size_t)(b * SEQ + XL + 1 + r) * DMODEL;
    u16* dst = cbuf + (size_t)i * DMODEL;
    int t = threadIdx.x;
    ((ushort2*)dst)[t] = ((const ushort2*)src)[t];
    if (t == 0) ctgt[i] = y[g];
}

// ---------------- CE + top-3 over compacted rows (sums 2 logits partials) ----------------
__global__ __launch_bounds__(256) void ce_kernel(
    const int* __restrict__ cnt,
    const float* __restrict__ lg0, const float* __restrict__ lg1,
    const int* __restrict__ ctgt, float* __restrict__ accum)
{
    int row = blockIdx.x;
    if (row >= *cnt) return;
    const float* lp0 = lg0 + (size_t)row * OV;
    const float* lp1 = lg1 + (size_t)row * OV;
    int tgt = ctgt[row];
    int t = threadIdx.x;
    __shared__ float red[4];

    float lmax = -INFINITY;
    for (int i = t; i < OV; i += 256) lmax = fmaxf(lmax, lp0[i] + lp1[i]);
    #pragma unroll
    for (int off = 32; off > 0; off >>= 1) lmax = fmaxf(lmax, __shfl_xor(lmax, off));
    if ((t & 63) == 0) red[t >> 6] = lmax;
    __syncthreads();
    lmax = fmaxf(fmaxf(red[0], red[1]), fmaxf(red[2], red[3]));
    __syncthreads();

    float lsum = 0.f;
    for (int i = t; i < OV; i += 256) lsum += expf(lp0[i] + lp1[i] - lmax);
    #pragma unroll
    for (int off = 32; off > 0; off >>= 1) lsum += __shfl_xor(lsum, off);
    if ((t & 63) == 0) red[t >> 6] = lsum;
    __syncthreads();
    lsum = red[0] + red[1] + red[2] + red[3];
    __syncthreads();

    float lt = lp0[tgt] + lp1[tgt];
    float cntr = 0.f;
    for (int i = t; i < OV; i += 256) {
        float v = lp0[i] + lp1[i];
        if (v > lt || (v == lt && i < tgt)) cntr += 1.f;
    }
    #pragma unroll
    for (int off = 32; off > 0; off >>= 1) cntr += __shfl_xor(cntr, off);
    if ((t & 63) == 0) red[t >> 6] = cntr;
    __syncthreads();
    cntr = red[0] + red[1] + red[2] + red[3];

    if (t == 0) {
        float ce = -(lt - lmax - logf(lsum));
        float inc = (tgt != EOS_TOK) ? 1.f : 0.f;
        float corr = (cntr < 2.5f) ? 1.f : 0.f;
        atomicAdd(&accum[0], ce);
        atomicAdd(&accum[1], 1.f);
        atomicAdd(&accum[2], corr * inc);
        atomicAdd(&accum[3], inc);
    }
}

// ---------------- duration head ----------------
__global__ __launch_bounds__(256) void dur1_kernel(
    const float* __restrict__ hbuf, const int* __restrict__ y1_lens,
    const float* __restrict__ dW1, const float* __restrict__ db1,
    float* __restrict__ h1buf)
{
    __shared__ float cls[DMODEL];
    int g = blockIdx.x;
    int b = g >> 3, c = g & 7;
    int t = threadIdx.x;
    const float* cp = hbuf + (size_t)(b * SEQ + XL + 1 + y1_lens[b]) * DMODEL;
    cls[t] = cp[t]; cls[t + 256] = cp[t + 256];
    __syncthreads();
    int row = c * 32 + (t >> 3);
    int ln = t & 7;
    const float* w = dW1 + (size_t)row * DMODEL + ln * 64;
    const float* cv = cls + ln * 64;
    float acc = 0.f;
    #pragma unroll 8
    for (int k = 0; k < 64; ++k) acc = fmaf(cv[k], w[k], acc);
    acc += __shfl_xor(acc, 1); acc += __shfl_xor(acc, 2); acc += __shfl_xor(acc, 4);
    if (ln == 0) h1buf[b * 256 + row] = fmaxf(acc + db1[row], 0.f);
}

__global__ __launch_bounds__(256) void dur2_kernel(
    const float* __restrict__ h1buf,
    const float* __restrict__ dW2, const float* __restrict__ db2,
    const float* __restrict__ dW3, const float* __restrict__ db3,
    float* __restrict__ preds)
{
    __shared__ float h1s[256];
    __shared__ float h2s[128];
    int b = blockIdx.x;
    int t = threadIdx.x;
    h1s[t] = h1buf[b * 256 + t];
    __syncthreads();
    if (t < 128) {
        float acc = db2[t];
        const float* w = dW2 + (size_t)t * 256;
        for (int k = 0; k < 256; ++k) acc = fmaf(h1s[k], w[k], acc);
        h2s[t] = fmaxf(acc, 0.f);
    }
    __syncthreads();
    if (t < 64) {
        float v = h2s[t] * dW3[t] + h2s[t + 64] * dW3[t + 64];
        #pragma unroll
        for (int off = 32; off > 0; off >>= 1) v += __shfl_xor(v, off);
        if (t == 0) preds[b] = v + db3[0];
    }
}

__global__ __launch_bounds__(64) void final_kernel(
    const float* __restrict__ accum, const float* __restrict__ preds,
    const int* __restrict__ y2_lens, const int* __restrict__ x2_lens,
    float* __restrict__ out)
{
    if (threadIdx.x == 0) {
        float dl = 0.f;
        for (int b = 0; b < BATCH; ++b) {
            float tgt = (float)y2_lens[b] / (float)x2_lens[b];
            float e = preds[b] - tgt;
            float ae = fabsf(e);
            dl += (ae <= 1.f) ? 0.5f * e * e : (ae - 0.5f);
        }
        dl *= (1.f / BATCH);
        float token_loss = accum[0] / accum[1];
        float acc_v = accum[2] / fmaxf(accum[3], 1.f);
        out[0] = token_loss + dl;
        out[1] = acc_v;
    }
}

// ---------------- orchestration ----------------
extern "C" void kernel_launch(void* const* d_in, const int* in_sizes, int n_in,
                              void* d_out, int out_size, void* d_ws, size_t ws_size,
                              hipStream_t stream)
{
    const int*   x           = (const int*)d_in[0];
    const int*   x1_lens     = (const int*)d_in[1];
    const int*   x2_lens     = (const int*)d_in[2];
    const int*   y           = (const int*)d_in[3];
    const int*   y1_lens     = (const int*)d_in[4];
    const int*   y2_lens     = (const int*)d_in[5];
    const int*   y_mask      = (const int*)d_in[6];
    const float* emo_feature = (const float*)d_in[7];
    const float* text_emb    = (const float*)d_in[8];
    const float* audio_emb   = (const float*)d_in[9];
    const float* type_emb    = (const float*)d_in[10];
    const float* emo_W       = (const float*)d_in[11];
    const float* emo_b       = (const float*)d_in[12];
    const float* alpha_text  = (const float*)d_in[13];
    const float* alpha_audio = (const float*)d_in[14];
    const float* Wqkv        = (const float*)d_in[15];
    const float* bqkv        = (const float*)d_in[16];
    const float* Wo          = (const float*)d_in[17];
    const float* bo          = (const float*)d_in[18];
    const float* ln1_g       = (const float*)d_in[19];
    const float* ln1_b       = (const float*)d_in[20];
    const float* ln2_g       = (const float*)d_in[21];
    const float* ln2_b       = (const float*)d_in[22];
    const float* W1          = (const float*)d_in[23];
    const float* b1          = (const float*)d_in[24];
    const float* W2          = (const float*)d_in[25];
    const float* b2          = (const float*)d_in[26];
    const float* predict_W   = (const float*)d_in[27];
    const float* dW1         = (const float*)d_in[28];
    const float* db1         = (const float*)d_in[29];
    const float* dW2         = (const float*)d_in[30];
    const float* db2         = (const float*)d_in[31];
    const float* dW3         = (const float*)d_in[32];
    const float* db3         = (const float*)d_in[33];

    const int M = BATCH * SEQ;                       // 4612
    char* p = (char*)d_ws;
    float* hbuf   = (float*)p; p += 9445376;         // M*512*4
    float* delta  = (float*)p; p += 9445376;
    char*  uni    = p;         p += 18909440;        // ff1_bf | logits lg0 | attn opart
    u16*   hbuf_bf = (u16*)p;  p += 4722688;
    u16*   qkv_bf  = (u16*)p;  p += 14168064;        // also split-K partial region
    u16*   obuf_bf = (u16*)p;  p += 4722688;
    u16*   wbf     = (u16*)p;  p += 19923968;
    u16*   cbuf    = (u16*)p;  p += (size_t)CCAP * DMODEL * 2;
    u16*   ff1_bf  = (u16*)uni;

    float* partA = (float*)qkv_bf;
    float* partB = (float*)((char*)qkv_bf + 9445376);
    float* lg0   = (float*)uni;
    float* lg1   = (float*)qkv_bf;
    float* opart = (float*)uni;                      // 2 x NROWS x 64 f32 = 18.9MB (ff1 dead)
    float* mlbuf = delta;                            // 4 x NROWS f32 (delta dead during attn)

    float* accum  = delta;
    int*   cnt    = (int*)(delta + 4);
    float* preds  = delta + 8;
    int*   cmap   = (int*)(delta + 16);
    int*   ctgt   = cmap + CCAP;
    float* h1buf  = (float*)(ctgt + CCAP);

    u16* wq_bf = wbf;                                // 3*1536*512
    u16* wo_bf = wq_bf + 2359296;                    // 3*512*512
    u16* w1_bf = wo_bf + 786432;                     // 3*2048*512
    u16* w2_bf = w1_bf + 3145728;                    // 3*512*2048
    u16* wp_bf = w2_bf + 3145728;                    // 1025*512

    cvt5_kernel<<<1024, 256, 0, stream>>>(
        Wqkv, wq_bf, 2359296 / 4,
        Wo, wo_bf, 786432 / 4,
        W1, w1_bf, 3145728 / 4,
        W2, w2_bf, 3145728 / 4,
        predict_W, wp_bf, 524800 / 4);

    emo_kernel<<<32, 256, 0, stream>>>(emo_feature, emo_W, emo_b, type_emb, hbuf, hbuf_bf);
    build_h_kernel<<<M / 4, 256, 0, stream>>>(
        x, y, y_mask, text_emb, audio_emb, type_emb,
        alpha_text, alpha_audio, hbuf, hbuf_bf);

    const int MG = (M + 127) / 128;   // 37
    for (int l = 0; l < NLAYER; ++l) {
        gemm_bf16_kernel<<<dim3(12, MG), 256, 0, stream>>>(
            hbuf_bf, wq_bf + (size_t)l * 1536 * 512, bqkv + l * 1536,
            nullptr, qkv_bf, M, 1536, 512, 0);
        attn_mfma_kernel<<<dim3((SEQ + QBLK - 1) / QBLK, BATCH * NH, 2), 512, 0, stream>>>(
            qkv_bf, x1_lens, x2_lens, y1_lens, y2_lens, y_mask, opart, mlbuf);
        attn_merge_kernel<<<NROWS / 4, 256, 0, stream>>>(opart, mlbuf, obuf_bf);
        gemm_bf16_splitk_kernel<<<dim3(4, MG, 2), 256, 0, stream>>>(
            obuf_bf, wo_bf + (size_t)l * 512 * 512,
            delta, partA, nullptr, M, 512, 512, 256);
        add_ln_kernel<<<M / 4, 256, 0, stream>>>(hbuf, hbuf_bf,
            delta, partA, nullptr, bo + l * 512,
            ln1_g + l * DMODEL, ln1_b + l * DMODEL);
        gemm_bf16_kernel<<<dim3(16, MG), 256, 0, stream>>>(
            hbuf_bf, w1_bf + (size_t)l * 2048 * 512, b1 + l * 2048,
            nullptr, ff1_bf, M, 2048, 512, 1);
        gemm_bf16_splitk_kernel<<<dim3(4, MG, 3), 256, 0, stream>>>(
            ff1_bf, w2_bf + (size_t)l * 512 * 2048,
            delta, partA, partB, M, 512, 2048, 768);
        add_ln_kernel<<<M / 4, 256, 0, stream>>>(hbuf, hbuf_bf,
            delta, partA, partB, b2 + l * 512,
            ln2_g + l * DMODEL, ln2_b + l * DMODEL);
    }

    init_accum_kernel<<<1, 64, 0, stream>>>(accum);
    compact_kernel<<<(BATCH * YL) / 256, 256, 0, stream>>>(y_mask, cnt, cmap);
    copy_rows_kernel<<<CCAP, 256, 0, stream>>>(cnt, cmap, hbuf_bf, y, cbuf, ctgt);
    gemm_bf16_splitk_dynm_kernel<<<dim3((OV + 127) / 128, CCAP / 128, 2), 256, 0, stream>>>(
        cbuf, wp_bf, cnt, lg0, lg1, OV, 512, 256);
    ce_kernel<<<CCAP, 256, 0, stream>>>(cnt, lg0, lg1, ctgt, accum);

    dur1_kernel<<<32, 256, 0, stream>>>(hbuf, y1_lens, dW1, db1, h1buf);
    dur2_kernel<<<4, 256, 0, stream>>>(h1buf, dW2, db2, dW3, db3, preds);
    final_kernel<<<1, 64, 0, stream>>>(accum, preds, y2_lens, x2_lens, (float*)d_out);
}

// Round 11
// 527.655 us; speedup vs baseline: 1.3762x; 1.1344x over previous
//
#include <hip/hip_runtime.h>
#include <hip/hip_bf16.h>
#include <math.h>

#define BATCH 4
#define XL 128
#define YL 1024
#define DMODEL 512
#define NH 8
#define NLAYER 3
#define DFF 2048
#define MASK_ID 1024
#define EOS_TOK 1024
#define HD 64
#define SEQ 1153          // XL + 1 + YL
#define OV 1025
#define NEGBIG (-1e9f)
#define QBLK 128
#define CCAP 2432         // max compacted masked rows
#define NROWS 36896       // BATCH*SEQ*NH

typedef unsigned short u16;
typedef unsigned int u32;
typedef short short8 __attribute__((ext_vector_type(8)));
typedef float f32x4 __attribute__((ext_vector_type(4)));

__device__ __forceinline__ u16 f2bf(float f) {
    union { float f; unsigned u; } v; v.f = f;
    unsigned r = v.u + 0x7fffu + ((v.u >> 16) & 1u);   // RNE
    return (u16)(r >> 16);
}
__device__ __forceinline__ float bf2f(u16 b) {
    union { unsigned u; float f; } v; v.u = ((unsigned)b) << 16;
    return v.f;
}

// ---------------- fused f32 -> bf16 convert for all 5 weight tensors ----------------
__global__ __launch_bounds__(256) void cvt5_kernel(
    const float* __restrict__ s0, u16* __restrict__ d0, int n0,
    const float* __restrict__ s1, u16* __restrict__ d1, int n1,
    const float* __restrict__ s2, u16* __restrict__ d2, int n2,
    const float* __restrict__ s3, u16* __restrict__ d3, int n3,
    const float* __restrict__ s4, u16* __restrict__ d4, int n4)
{
    int c0 = n0, c1 = c0 + n1, c2 = c1 + n2, c3 = c2 + n3, c4 = c3 + n4;
    for (int i = blockIdx.x * 256 + threadIdx.x; i < c4; i += gridDim.x * 256) {
        const float* s; u16* d; int j;
        if (i < c0)      { s = s0; d = d0; j = i; }
        else if (i < c1) { s = s1; d = d1; j = i - c0; }
        else if (i < c2) { s = s2; d = d2; j = i - c1; }
        else if (i < c3) { s = s3; d = d3; j = i - c2; }
        else             { s = s4; d = d4; j = i - c3; }
        float4 v = ((const float4*)s)[j];
        ushort4 o;
        o.x = f2bf(v.x); o.y = f2bf(v.y); o.z = f2bf(v.z); o.w = f2bf(v.w);
        ((ushort4*)d)[j] = o;
    }
}

// ---------------- emo rows ----------------
__global__ __launch_bounds__(256) void emo_kernel(
    const float* __restrict__ emo_feature, const float* __restrict__ emo_W,
    const float* __restrict__ emo_b, const float* __restrict__ type_emb,
    float* __restrict__ hbuf, u16* __restrict__ hbuf_bf)
{
    int b = blockIdx.x >> 3, c = blockIdx.x & 7;
    int t = threadIdx.x;
    int osub = t >> 2, ln = t & 3;
    int d = c * 64 + osub;
    const float* f = emo_feature + b * 768 + ln * 192;
    const float* w = emo_W + (size_t)d * 768 + ln * 192;
    float acc = 0.f;
    #pragma unroll 4
    for (int k = 0; k < 192; ++k) acc = fmaf(f[k], w[k], acc);
    acc += __shfl_xor(acc, 1);
    acc += __shfl_xor(acc, 2);
    if (ln == 0) {
        float v = acc + emo_b[d] + type_emb[DMODEL + d];
        hbuf[(size_t)(b * SEQ + XL) * DMODEL + d] = v;
        hbuf_bf[(size_t)(b * SEQ + XL) * DMODEL + d] = f2bf(v);
    }
}

// ---------------- build h_input (x & y rows), wave-per-row ----------------
__global__ __launch_bounds__(256) void build_h_kernel(
    const int* __restrict__ x, const int* __restrict__ y, const int* __restrict__ y_mask,
    const float* __restrict__ text_emb, const float* __restrict__ audio_emb,
    const float* __restrict__ type_emb,
    const float* __restrict__ alpha_text, const float* __restrict__ alpha_audio,
    float* __restrict__ hbuf, u16* __restrict__ hbuf_bf)
{
    int row = blockIdx.x * 4 + (threadIdx.x >> 6);
    int l = threadIdx.x & 63;
    int b = row / SEQ, s = row % SEQ;
    if (s == XL) return;
    int d0 = l * 8;

    const float* emb; const float* te; float alpha; int pos;
    if (s < XL) {
        int tok = x[b * XL + s];
        emb = text_emb + (size_t)tok * DMODEL;
        te = type_emb; alpha = alpha_text[0]; pos = s;
    } else {
        int r = s - XL - 1;
        int tok = y_mask[b * YL + r] ? MASK_ID : y[b * YL + r];
        emb = audio_emb + (size_t)tok * DMODEL;
        te = type_emb + 2 * DMODEL; alpha = alpha_audio[0]; pos = r;
    }

    float4 e0 = *(const float4*)(emb + d0);
    float4 e1 = *(const float4*)(emb + d0 + 4);
    float4 t0 = *(const float4*)(te + d0);
    float4 t1 = *(const float4*)(te + d0 + 4);
    float v[8] = {e0.x + t0.x, e0.y + t0.y, e0.z + t0.z, e0.w + t0.w,
                  e1.x + t1.x, e1.y + t1.y, e1.z + t1.z, e1.w + t1.w};
    float fp = (float)pos;
    #pragma unroll
    for (int p = 0; p < 4; ++p) {
        int d = d0 + 2 * p;
        float div = __expf((float)d * (-9.210340371976184f / (float)DMODEL));
        float sn, cs;
        __sincosf(fp * div, &sn, &cs);
        v[2 * p]     += alpha * sn;
        v[2 * p + 1] += alpha * cs;
    }

    float* hp = hbuf + (size_t)row * DMODEL + d0;
    *(float4*)hp       = make_float4(v[0], v[1], v[2], v[3]);
    *(float4*)(hp + 4) = make_float4(v[4], v[5], v[6], v[7]);
    short8 sv;
    #pragma unroll
    for (int e = 0; e < 8; ++e) sv[e] = (short)f2bf(v[e]);
    *(short8*)(hbuf_bf + (size_t)row * DMODEL + d0) = sv;
}

// ======= bf16 MFMA NT GEMM, 128x128 tile, 8 waves (4x2), one gload_lds/thread =======
__global__ __launch_bounds__(512) void gemm_bf16_kernel(
    const u16* __restrict__ A, const u16* __restrict__ Bw,
    const float* __restrict__ bias,
    float* __restrict__ Cf, u16* __restrict__ Cb,
    int M, int N, int K, int relu)
{
    __shared__ u16 As[128 * 32];
    __shared__ u16 Bs[128 * 32];
    int tid = threadIdx.x;
    int w = tid >> 6, l = tid & 63;
    int m0 = blockIdx.y * 128, n0 = blockIdx.x * 128;
    int wm = (w >> 1) * 32, wn = (w & 1) * 64;

    f32x4 acc[2][4];
    #pragma unroll
    for (int i = 0; i < 2; ++i)
        #pragma unroll
        for (int j = 0; j < 4; ++j) acc[i][j] = (f32x4){0.f, 0.f, 0.f, 0.f};

    int srow = (w << 4) + (l >> 2);     // 0..127 (wave w owns rows 16w..16w+15)
    int skp = (l & 3) << 3;             // k elem 0/8/16/24

    for (int k0 = 0; k0 < K; k0 += 32) {
        {
            int am = m0 + srow; if (am >= M) am = M - 1;
            int bn = n0 + srow; if (bn >= N) bn = N - 1;
            __builtin_amdgcn_global_load_lds(
                (const __attribute__((address_space(1))) void*)(A + (size_t)am * K + k0 + skp),
                (__attribute__((address_space(3))) void*)(As + (w << 9)), 16, 0, 0);
            __builtin_amdgcn_global_load_lds(
                (const __attribute__((address_space(1))) void*)(Bw + (size_t)bn * K + k0 + skp),
                (__attribute__((address_space(3))) void*)(Bs + (w << 9)), 16, 0, 0);
        }
        __syncthreads();
        short8 af[2], bfr[4];
        #pragma unroll
        for (int i = 0; i < 2; ++i)
            af[i]  = *(const short8*)(As + (wm + i * 16 + (l & 15)) * 32 + ((l >> 4) << 3));
        #pragma unroll
        for (int j = 0; j < 4; ++j)
            bfr[j] = *(const short8*)(Bs + (wn + j * 16 + (l & 15)) * 32 + ((l >> 4) << 3));
        #pragma unroll
        for (int i = 0; i < 2; ++i)
            #pragma unroll
            for (int j = 0; j < 4; ++j)
                acc[i][j] = __builtin_amdgcn_mfma_f32_16x16x32_bf16(af[i], bfr[j], acc[i][j], 0, 0, 0);
        __syncthreads();
    }

    #pragma unroll
    for (int i = 0; i < 2; ++i) {
        #pragma unroll
        for (int j = 0; j < 4; ++j) {
            #pragma unroll
            for (int jj = 0; jj < 4; ++jj) {
                int row = m0 + wm + i * 16 + ((l >> 4) << 2) + jj;
                int col = n0 + wn + j * 16 + (l & 15);
                if (row < M && col < N) {
                    float v = acc[i][j][jj];
                    if (bias) v += bias[col];
                    if (relu) v = fmaxf(v, 0.f);
                    if (Cf) Cf[(size_t)row * N + col] = v;
                    if (Cb) Cb[(size_t)row * N + col] = f2bf(v);
                }
            }
        }
    }
}

// ---- split-K variant (8-wave) ----
__global__ __launch_bounds__(512) void gemm_bf16_splitk_kernel(
    const u16* __restrict__ A, const u16* __restrict__ Bw,
    float* __restrict__ P0, float* __restrict__ P1, float* __restrict__ P2,
    int M, int N, int K, int klen)
{
    __shared__ u16 As[128 * 32];
    __shared__ u16 Bs[128 * 32];
    int tid = threadIdx.x;
    int w = tid >> 6, l = tid & 63;
    int z = blockIdx.z;
    float* Cp = (z == 0) ? P0 : (z == 1) ? P1 : P2;
    int kbeg = z * klen;
    int kend = min(kbeg + klen, K);
    int m0 = blockIdx.y * 128, n0 = blockIdx.x * 128;
    int wm = (w >> 1) * 32, wn = (w & 1) * 64;

    f32x4 acc[2][4];
    #pragma unroll
    for (int i = 0; i < 2; ++i)
        #pragma unroll
        for (int j = 0; j < 4; ++j) acc[i][j] = (f32x4){0.f, 0.f, 0.f, 0.f};

    int srow = (w << 4) + (l >> 2);
    int skp = (l & 3) << 3;

    for (int k0 = kbeg; k0 < kend; k0 += 32) {
        {
            int am = m0 + srow; if (am >= M) am = M - 1;
            int bn = n0 + srow; if (bn >= N) bn = N - 1;
            __builtin_amdgcn_global_load_lds(
                (const __attribute__((address_space(1))) void*)(A + (size_t)am * K + k0 + skp),
                (__attribute__((address_space(3))) void*)(As + (w << 9)), 16, 0, 0);
            __builtin_amdgcn_global_load_lds(
                (const __attribute__((address_space(1))) void*)(Bw + (size_t)bn * K + k0 + skp),
                (__attribute__((address_space(3))) void*)(Bs + (w << 9)), 16, 0, 0);
        }
        __syncthreads();
        short8 af[2], bfr[4];
        #pragma unroll
        for (int i = 0; i < 2; ++i)
            af[i]  = *(const short8*)(As + (wm + i * 16 + (l & 15)) * 32 + ((l >> 4) << 3));
        #pragma unroll
        for (int j = 0; j < 4; ++j)
            bfr[j] = *(const short8*)(Bs + (wn + j * 16 + (l & 15)) * 32 + ((l >> 4) << 3));
        #pragma unroll
        for (int i = 0; i < 2; ++i)
            #pragma unroll
            for (int j = 0; j < 4; ++j)
                acc[i][j] = __builtin_amdgcn_mfma_f32_16x16x32_bf16(af[i], bfr[j], acc[i][j], 0, 0, 0);
        __syncthreads();
    }

    #pragma unroll
    for (int i = 0; i < 2; ++i) {
        #pragma unroll
        for (int j = 0; j < 4; ++j) {
            #pragma unroll
            for (int jj = 0; jj < 4; ++jj) {
                int row = m0 + wm + i * 16 + ((l >> 4) << 2) + jj;
                int col = n0 + wn + j * 16 + (l & 15);
                if (row < M && col < N)
                    Cp[(size_t)row * N + col] = acc[i][j][jj];
            }
        }
    }
}

// ---- split-K + dynamic-M (logits, 8-wave) ----
__global__ __launch_bounds__(512) void gemm_bf16_splitk_dynm_kernel(
    const u16* __restrict__ A, const u16* __restrict__ Bw,
    const int* __restrict__ Mp,
    float* __restrict__ P0, float* __restrict__ P1,
    int N, int K, int klen)
{
    int M = *Mp;
    int m0 = blockIdx.y * 128;
    if (m0 >= M) return;
    __shared__ u16 As[128 * 32];
    __shared__ u16 Bs[128 * 32];
    int tid = threadIdx.x;
    int w = tid >> 6, l = tid & 63;
    int z = blockIdx.z;
    float* Cp = (z == 0) ? P0 : P1;
    int kbeg = z * klen;
    int kend = min(kbeg + klen, K);
    int n0 = blockIdx.x * 128;
    int wm = (w >> 1) * 32, wn = (w & 1) * 64;

    f32x4 acc[2][4];
    #pragma unroll
    for (int i = 0; i < 2; ++i)
        #pragma unroll
        for (int j = 0; j < 4; ++j) acc[i][j] = (f32x4){0.f, 0.f, 0.f, 0.f};

    int srow = (w << 4) + (l >> 2);
    int skp = (l & 3) << 3;

    for (int k0 = kbeg; k0 < kend; k0 += 32) {
        {
            int am = m0 + srow; if (am >= M) am = M - 1;
            int bn = n0 + srow; if (bn >= N) bn = N - 1;
            __builtin_amdgcn_global_load_lds(
                (const __attribute__((address_space(1))) void*)(A + (size_t)am * K + k0 + skp),
                (__attribute__((address_space(3))) void*)(As + (w << 9)), 16, 0, 0);
            __builtin_amdgcn_global_load_lds(
                (const __attribute__((address_space(1))) void*)(Bw + (size_t)bn * K + k0 + skp),
                (__attribute__((address_space(3))) void*)(Bs + (w << 9)), 16, 0, 0);
        }
        __syncthreads();
        short8 af[2], bfr[4];
        #pragma unroll
        for (int i = 0; i < 2; ++i)
            af[i]  = *(const short8*)(As + (wm + i * 16 + (l & 15)) * 32 + ((l >> 4) << 3));
        #pragma unroll
        for (int j = 0; j < 4; ++j)
            bfr[j] = *(const short8*)(Bs + (wn + j * 16 + (l & 15)) * 32 + ((l >> 4) << 3));
        #pragma unroll
        for (int i = 0; i < 2; ++i)
            #pragma unroll
            for (int j = 0; j < 4; ++j)
                acc[i][j] = __builtin_amdgcn_mfma_f32_16x16x32_bf16(af[i], bfr[j], acc[i][j], 0, 0, 0);
        __syncthreads();
    }

    #pragma unroll
    for (int i = 0; i < 2; ++i) {
        #pragma unroll
        for (int j = 0; j < 4; ++j) {
            #pragma unroll
            for (int jj = 0; jj < 4; ++jj) {
                int row = m0 + wm + i * 16 + ((l >> 4) << 2) + jj;
                int col = n0 + wn + j * 16 + (l & 15);
                if (row < M && col < N)
                    Cp[(size_t)row * N + col] = acc[i][j][jj];
            }
        }
    }
}

// ============== MFMA flash attention (R7 structure) + K-SPLIT (flash-decoding) =======
__global__ __launch_bounds__(512) void attn_mfma_kernel(
    const u16* __restrict__ qkv,
    const int* __restrict__ x1_lens, const int* __restrict__ x2_lens,
    const int* __restrict__ y1_lens, const int* __restrict__ y2_lens,
    const int* __restrict__ y_mask,
    float* __restrict__ opart, float* __restrict__ ml)
{
    __shared__ u16 Ks[64 * 64];
    __shared__ u16 Vt[64 * 64];
    __shared__ unsigned long long Bits[7][19];

    int tid = threadIdx.x;
    int w = tid >> 6, l = tid & 63;
    int g = l >> 4;
    int q = l & 15;
    int bh = blockIdx.y;
    int b = bh >> 3, h = bh & 7;
    int q0 = blockIdx.x * QBLK;
    int z = blockIdx.z;

    int x1 = x1_lens[b], xlen = x1 + 1 + x2_lens[b];
    int y1 = y1_lens[b], ylen = y1 + 1 + y2_lens[b];

    int kmax = -1;
    if (q0 < XL) kmax = max(kmax, xlen - 1);
    if (XL >= q0 && XL < q0 + QBLK) kmax = max(kmax, XL);
    {
        int ry0 = max(0, q0 - XL - 1);
        int ry1 = min(YL - 1, q0 + QBLK - 2 - XL);
        if (ry0 <= ry1) {
            if (ry0 <= y1 - 1) kmax = max(kmax, XL + y1);
            if (y1 >= ry0 && y1 <= ry1) kmax = max(kmax, XL + y1 + 1);
            int a = max(ry0, y1 + 1), bb = min(ry1, ylen - 1);
            if (a <= bb) kmax = max(kmax, XL + ylen);
        }
    }
    if (kmax < 0) kmax = 0;
    int NKT = (kmax >> 6) + 1;
    int half = (NKT + 1) >> 1;
    int kbeg = z ? half : 0;
    int kend = z ? NKT : half;

    for (int pp = w; pp < 7 * 19; pp += 8) {
        int ty = pp / 19, tile = pp - ty * 19;
        int c = tile * 64 + l;
        bool allow = false;
        if (c < SEQ && ty < 6) {
            bool a2c = (c == XL), ygt = (c > XL);
            if (ty == 0) allow = (c < x1);
            else if (ty == 1) allow = (c >= x1) && (c < xlen);
            else if (ty == 2) allow = a2c;
            else if (ty == 3) allow = (c < x1) || (ygt && c <= XL + y1);
            else if (ty == 4) allow = (c < xlen) || a2c || (ygt && c <= XL + y1 + 1);
            else {
                int ym = ygt ? y_mask[b * YL + c - XL - 1] : 0;
                allow = (((c < xlen) || a2c || (ygt && c <= XL + ylen)) && !ym);
            }
        }
        unsigned long long mk = __ballot(allow);
        if (l == 0) Bits[ty][tile] = mk;
    }

    int qr = q0 + w * 16 + q;
    int qrc = min(qr, SEQ - 1);
    short8 qf0, qf1;
    {
        const u16* qp = qkv + (size_t)(b * SEQ + qrc) * 1536 + h * 64 + (g << 3);
        short8 r0 = *(const short8*)qp;
        short8 r1 = *(const short8*)(qp + 32);
        #pragma unroll
        for (int e = 0; e < 8; ++e) {
            qf0[e] = (short)f2bf(bf2f((u16)r0[e]) * 0.125f);
            qf1[e] = (short)f2bf(bf2f((u16)r1[e]) * 0.125f);
        }
    }

    int rt;
    {
        if (qr >= SEQ) rt = 6;
        else if (qr < XL) rt = (qr < x1) ? 0 : 1;
        else if (qr == XL) rt = 2;
        else {
            int ry = qr - XL - 1;
            rt = (ry < y1) ? 3 : (ry == y1) ? 4 : (ry < ylen) ? 5 : 6;
        }
    }

    f32x4 oacc[4];
    #pragma unroll
    for (int db = 0; db < 4; ++db) oacc[db] = (f32x4){0.f, 0.f, 0.f, 0.f};
    float mrun = -INFINITY, lrun = 0.f;

    int srcA = q + ((g & 1) << 5);
    int srcB = srcA + 16;
    bool hi = (g >> 1) & 1;

    for (int kt = kbeg; kt < kend; ++kt) {
        __syncthreads();
        {
            int r = tid >> 3, d0k = (tid & 7) << 3;
            int krc = min(kt * 64 + r, SEQ - 1);
            short8 ka = *(const short8*)(qkv + (size_t)(b * SEQ + krc) * 1536 + 512 + h * 64 + d0k);
            *(short8*)&Ks[r * 64 + (d0k ^ ((r & 7) << 3))] = ka;
        }
        {
            int rp = tid >> 4, o = tid & 15;
            int d0v = o * 4;
            int k0r = min(kt * 64 + 2 * rp, SEQ - 1);
            int k1r = min(kt * 64 + 2 * rp + 1, SEQ - 1);
            ushort4 va = *(const ushort4*)(qkv + (size_t)(b * SEQ + k0r) * 1536 + 1024 + h * 64 + d0v);
            ushort4 vb = *(const ushort4*)(qkv + (size_t)(b * SEQ + k1r) * 1536 + 1024 + h * 64 + d0v);
            u32 pv[4] = {(u32)va.x | ((u32)vb.x << 16), (u32)va.y | ((u32)vb.y << 16),
                         (u32)va.z | ((u32)vb.z << 16), (u32)va.w | ((u32)vb.w << 16)};
            #pragma unroll
            for (int e = 0; e < 4; ++e) {
                int d = d0v + e;
                *(u32*)&Vt[d * 64 + ((2 * rp) ^ ((d & 7) << 3))] = pv[e];
            }
        }
        __syncthreads();

        f32x4 sc[4];
        #pragma unroll
        for (int cb = 0; cb < 4; ++cb) {
            int krw = cb * 16 + q;
            int ksw = (krw & 7) << 3;
            short8 k0 = *(const short8*)&Ks[krw * 64 + ((g << 3) ^ ksw)];
            short8 k1 = *(const short8*)&Ks[krw * 64 + ((32 + (g << 3)) ^ ksw)];
            f32x4 zz = (f32x4){0.f, 0.f, 0.f, 0.f};
            zz = __builtin_amdgcn_mfma_f32_16x16x32_bf16(k0, qf0, zz, 0, 0, 0);
            sc[cb] = __builtin_amdgcn_mfma_f32_16x16x32_bf16(k1, qf1, zz, 0, 0, 0);
        }

        unsigned long long mb = Bits[rt][kt];
        #pragma unroll
        for (int cb = 0; cb < 4; ++cb) {
            unsigned nib = (unsigned)(mb >> (16 * cb + 4 * g)) & 0xFu;
            #pragma unroll
            for (int r = 0; r < 4; ++r)
                sc[cb][r] = ((nib >> r) & 1u) ? sc[cb][r] : NEGBIG;
        }

        float tmax = sc[0][0];
        #pragma unroll
        for (int cb = 0; cb < 4; ++cb)
            #pragma unroll
            for (int r = 0; r < 4; ++r) tmax = fmaxf(tmax, sc[cb][r]);
        tmax = fmaxf(tmax, __shfl_xor(tmax, 16));
        tmax = fmaxf(tmax, __shfl_xor(tmax, 32));
        float newm = fmaxf(mrun, tmax);
        float corr = __expf(mrun - newm);
        float p[4][4];
        float ps = 0.f;
        #pragma unroll
        for (int cb = 0; cb < 4; ++cb)
            #pragma unroll
            for (int r = 0; r < 4; ++r) {
                p[cb][r] = __expf(sc[cb][r] - newm);
                ps += p[cb][r];
            }
        ps += __shfl_xor(ps, 16);
        ps += __shfl_xor(ps, 32);
        lrun = lrun * corr + ps;
        mrun = newm;

        float cr[4];
        #pragma unroll
        for (int r = 0; r < 4; ++r) cr[r] = __shfl(corr, (g << 2) + r);
        #pragma unroll
        for (int db = 0; db < 4; ++db)
            #pragma unroll
            for (int r = 0; r < 4; ++r) oacc[db][r] *= cr[r];

        u32 P0[4], P1[4];
        #pragma unroll
        for (int cb = 0; cb < 4; ++cb) {
            P0[cb] = (u32)f2bf(p[cb][0]) | ((u32)f2bf(p[cb][1]) << 16);
            P1[cb] = (u32)f2bf(p[cb][2]) | ((u32)f2bf(p[cb][3]) << 16);
        }

        union { u32 u[4]; short8 s; } f1, f2;
        {
            u32 a0 = __shfl(P0[0], srcA), a1 = __shfl(P1[0], srcA);
            u32 a2 = __shfl(P0[0], srcB), a3 = __shfl(P1[0], srcB);
            u32 b0 = __shfl(P0[1], srcA), b1 = __shfl(P1[1], srcA);
            u32 b2 = __shfl(P0[1], srcB), b3 = __shfl(P1[1], srcB);
            f1.u[0] = hi ? b0 : a0; f1.u[1] = hi ? b1 : a1;
            f1.u[2] = hi ? b2 : a2; f1.u[3] = hi ? b3 : a3;
            u32 c0 = __shfl(P0[2], srcA), c1 = __shfl(P1[2], srcA);
            u32 c2 = __shfl(P0[2], srcB), c3 = __shfl(P1[2], srcB);
            u32 d0 = __shfl(P0[3], srcA), d1 = __shfl(P1[3], srcA);
            u32 d2 = __shfl(P0[3], srcB), d3 = __shfl(P1[3], srcB);
            f2.u[0] = hi ? d0 : c0; f2.u[1] = hi ? d1 : c1;
            f2.u[2] = hi ? d2 : c2; f2.u[3] = hi ? d3 : c3;
        }

        #pragma unroll
        for (int db = 0; db < 4; ++db) {
            int vr = db * 16 + q;
            int vsw = (vr & 7) << 3;
            short8 v0 = *(const short8*)&Vt[vr * 64 + ((g << 3) ^ vsw)];
            short8 v1 = *(const short8*)&Vt[vr * 64 + ((32 + (g << 3)) ^ vsw)];
            oacc[db] = __builtin_amdgcn_mfma_f32_16x16x32_bf16(f1.s, v0, oacc[db], 0, 0, 0);
            oacc[db] = __builtin_amdgcn_mfma_f32_16x16x32_bf16(f2.s, v1, oacc[db], 0, 0, 0);
        }
    }

    if (g == 0) {
        int row = q0 + w * 16 + q;
        if (row < SEQ) {
            int ridx = (b * SEQ + row) * 8 + h;
            ml[(size_t)(z * 2) * NROWS + ridx] = mrun;
            ml[(size_t)(z * 2 + 1) * NROWS + ridx] = lrun;
        }
    }
    float* op = opart + (size_t)z * NROWS * 64;
    #pragma unroll
    for (int db = 0; db < 4; ++db) {
        #pragma unroll
        for (int r = 0; r < 4; ++r) {
            int qrj = q0 + w * 16 + (g << 2) + r;
            if (qrj < SEQ) {
                int ridx = (b * SEQ + qrj) * 8 + h;
                op[(size_t)ridx * 64 + db * 16 + q] = oacc[db][r];
            }
        }
    }
}

// ---- merge the two k-splits ----
__global__ __launch_bounds__(256) void attn_merge_kernel(
    const float* __restrict__ opart, const float* __restrict__ ml,
    u16* __restrict__ obuf)
{
    int r = blockIdx.x * 4 + (threadIdx.x >> 6);
    int d = threadIdx.x & 63;
    float m0 = ml[r], l0 = ml[NROWS + r];
    float m1 = ml[2 * NROWS + r], l1 = ml[3 * NROWS + r];
    float M = fmaxf(m0, m1);
    float w0 = __expf(m0 - M), w1 = __expf(m1 - M);
    float denom = w0 * l0 + w1 * l1;
    float o0 = opart[(size_t)r * 64 + d];
    float o1 = opart[(size_t)(NROWS + r) * 64 + d];
    float v = (w0 * o0 + w1 * o1) / denom;
    int bs = r >> 3, h = r & 7;
    obuf[(size_t)bs * DMODEL + h * 64 + d] = f2bf(v);
}

// ------- residual add + fused split-K reduce (+bias) + LayerNorm, wave-per-row -------
__global__ __launch_bounds__(256) void add_ln_kernel(
    float* __restrict__ hbuf, u16* __restrict__ hbuf_bf,
    const float* __restrict__ p0, const float* __restrict__ p1,
    const float* __restrict__ p2, const float* __restrict__ bias,
    const float* __restrict__ g, const float* __restrict__ beta)
{
    int row = blockIdx.x * 4 + (threadIdx.x >> 6);
    int l = threadIdx.x & 63;
    int d0 = l * 8;
    size_t off = (size_t)row * DMODEL + d0;
    float* hp = hbuf + off;
    float4 a0 = *(const float4*)hp, a1 = *(const float4*)(hp + 4);
    float4 q0 = *(const float4*)(p0 + off), q1 = *(const float4*)(p0 + off + 4);
    float v[8] = {a0.x + q0.x, a0.y + q0.y, a0.z + q0.z, a0.w + q0.w,
                  a1.x + q1.x, a1.y + q1.y, a1.z + q1.z, a1.w + q1.w};
    if (p1) {
        float4 r0 = *(const float4*)(p1 + off), r1 = *(const float4*)(p1 + off + 4);
        v[0] += r0.x; v[1] += r0.y; v[2] += r0.z; v[3] += r0.w;
        v[4] += r1.x; v[5] += r1.y; v[6] += r1.z; v[7] += r1.w;
    }
    if (p2) {
        float4 r0 = *(const float4*)(p2 + off), r1 = *(const float4*)(p2 + off + 4);
        v[0] += r0.x; v[1] += r0.y; v[2] += r0.z; v[3] += r0.w;
        v[4] += r1.x; v[5] += r1.y; v[6] += r1.z; v[7] += r1.w;
    }
    {
        float4 b0 = *(const float4*)(bias + d0), b1 = *(const float4*)(bias + d0 + 4);
        v[0] += b0.x; v[1] += b0.y; v[2] += b0.z; v[3] += b0.w;
        v[4] += b1.x; v[5] += b1.y; v[6] += b1.z; v[7] += b1.w;
    }
    float s = 0.f;
    #pragma unroll
    for (int e = 0; e < 8; ++e) s += v[e];
    #pragma unroll
    for (int off2 = 32; off2 > 0; off2 >>= 1) s += __shfl_xor(s, off2);
    float mu = s * (1.f / DMODEL);
    float sq = 0.f;
    #pragma unroll
    for (int e = 0; e < 8; ++e) { v[e] -= mu; sq += v[e] * v[e]; }
    #pragma unroll
    for (int off2 = 32; off2 > 0; off2 >>= 1) sq += __shfl_xor(sq, off2);
    float inv = 1.f / sqrtf(sq * (1.f / DMODEL) + 1e-5f);
    float4 g0 = *(const float4*)(g + d0), g1 = *(const float4*)(g + d0 + 4);
    float4 be0 = *(const float4*)(beta + d0), be1 = *(const float4*)(beta + d0 + 4);
    float o[8];
    o[0] = v[0] * inv * g0.x + be0.x; o[1] = v[1] * inv * g0.y + be0.y;
    o[2] = v[2] * inv * g0.z + be0.z; o[3] = v[3] * inv * g0.w + be0.w;
    o[4] = v[4] * inv * g1.x + be1.x; o[5] = v[5] * inv * g1.y + be1.y;
    o[6] = v[6] * inv * g1.z + be1.z; o[7] = v[7] * inv * g1.w + be1.w;
    *(float4*)hp       = make_float4(o[0], o[1], o[2], o[3]);
    *(float4*)(hp + 4) = make_float4(o[4], o[5], o[6], o[7]);
    short8 sv;
    #pragma unroll
    for (int e = 0; e < 8; ++e) sv[e] = (short)f2bf(o[e]);
    *(short8*)(hbuf_bf + off) = sv;
}

// ---------------- compaction of masked rows ----------------
__global__ __launch_bounds__(256) void init_accum_kernel(float* accum) {
    if (threadIdx.x < 8) accum[threadIdx.x] = 0.f;
}

__global__ __launch_bounds__(256) void compact_kernel(
    const int* __restrict__ y_mask, int* __restrict__ cnt, int* __restrict__ cmap)
{
    int i = blockIdx.x * 256 + threadIdx.x;
    if (i < BATCH * YL && y_mask[i]) {
        int pos = atomicAdd(cnt, 1);
        cmap[pos] = i;
    }
}

__global__ __launch_bounds__(256) void copy_rows_kernel(
    const int* __restrict__ cnt, const int* __restrict__ cmap,
    const u16* __restrict__ hbuf_bf, const int* __restrict__ y,
    u16* __restrict__ cbuf, int* __restrict__ ctgt)
{
    int i = blockIdx.x;
    if (i >= *cnt) return;
    int g = cmap[i];
    int b = g >> 10, r = g & 1023;
    const u16* src = hbuf_bf + (size_t)(b * SEQ + XL + 1 + r) * DMODEL;
    u16* dst = cbuf + (size_t)i * DMODEL;
    int t = threadIdx.x;
    ((ushort2*)dst)[t] = ((const ushort2*)src)[t];
    if (t == 0) ctgt[i] = y[g];
}

// ---------------- CE + top-3 over compacted rows (sums 2 logits partials) ----------------
__global__ __launch_bounds__(256) void ce_kernel(
    const int* __restrict__ cnt,
    const float* __restrict__ lg0, const float* __restrict__ lg1,
    const int* __restrict__ ctgt, float* __restrict__ accum)
{
    int row = blockIdx.x;
    if (row >= *cnt) return;
    const float* lp0 = lg0 + (size_t)row * OV;
    const float* lp1 = lg1 + (size_t)row * OV;
    int tgt = ctgt[row];
    int t = threadIdx.x;
    __shared__ float red[4];

    float lmax = -INFINITY;
    for (int i = t; i < OV; i += 256) lmax = fmaxf(lmax, lp0[i] + lp1[i]);
    #pragma unroll
    for (int off = 32; off > 0; off >>= 1) lmax = fmaxf(lmax, __shfl_xor(lmax, off));
    if ((t & 63) == 0) red[t >> 6] = lmax;
    __syncthreads();
    lmax = fmaxf(fmaxf(red[0], red[1]), fmaxf(red[2], red[3]));
    __syncthreads();

    float lsum = 0.f;
    for (int i = t; i < OV; i += 256) lsum += expf(lp0[i] + lp1[i] - lmax);
    #pragma unroll
    for (int off = 32; off > 0; off >>= 1) lsum += __shfl_xor(lsum, off);
    if ((t & 63) == 0) red[t >> 6] = lsum;
    __syncthreads();
    lsum = red[0] + red[1] + red[2] + red[3];
    __syncthreads();

    float lt = lp0[tgt] + lp1[tgt];
    float cntr = 0.f;
    for (int i = t; i < OV; i += 256) {
        float v = lp0[i] + lp1[i];
        if (v > lt || (v == lt && i < tgt)) cntr += 1.f;
    }
    #pragma unroll
    for (int off = 32; off > 0; off >>= 1) cntr += __shfl_xor(cntr, off);
    if ((t & 63) == 0) red[t >> 6] = cntr;
    __syncthreads();
    cntr = red[0] + red[1] + red[2] + red[3];

    if (t == 0) {
        float ce = -(lt - lmax - logf(lsum));
        float inc = (tgt != EOS_TOK) ? 1.f : 0.f;
        float corr = (cntr < 2.5f) ? 1.f : 0.f;
        atomicAdd(&accum[0], ce);
        atomicAdd(&accum[1], 1.f);
        atomicAdd(&accum[2], corr * inc);
        atomicAdd(&accum[3], inc);
    }
}

// ---------------- duration head ----------------
__global__ __launch_bounds__(256) void dur1_kernel(
    const float* __restrict__ hbuf, const int* __restrict__ y1_lens,
    const float* __restrict__ dW1, const float* __restrict__ db1,
    float* __restrict__ h1buf)
{
    __shared__ float cls[DMODEL];
    int g = blockIdx.x;
    int b = g >> 3, c = g & 7;
    int t = threadIdx.x;
    const float* cp = hbuf + (size_t)(b * SEQ + XL + 1 + y1_lens[b]) * DMODEL;
    cls[t] = cp[t]; cls[t + 256] = cp[t + 256];
    __syncthreads();
    int row = c * 32 + (t >> 3);
    int ln = t & 7;
    const float* w = dW1 + (size_t)row * DMODEL + ln * 64;
    const float* cv = cls + ln * 64;
    float acc = 0.f;
    #pragma unroll 8
    for (int k = 0; k < 64; ++k) acc = fmaf(cv[k], w[k], acc);
    acc += __shfl_xor(acc, 1); acc += __shfl_xor(acc, 2); acc += __shfl_xor(acc, 4);
    if (ln == 0) h1buf[b * 256 + row] = fmaxf(acc + db1[row], 0.f);
}

__global__ __launch_bounds__(256) void dur2_kernel(
    const float* __restrict__ h1buf,
    const float* __restrict__ dW2, const float* __restrict__ db2,
    const float* __restrict__ dW3, const float* __restrict__ db3,
    float* __restrict__ preds)
{
    __shared__ float h1s[256];
    __shared__ float h2s[128];
    int b = blockIdx.x;
    int t = threadIdx.x;
    h1s[t] = h1buf[b * 256 + t];
    __syncthreads();
    if (t < 128) {
        float acc = db2[t];
        const float* w = dW2 + (size_t)t * 256;
        for (int k = 0; k < 256; ++k) acc = fmaf(h1s[k], w[k], acc);
        h2s[t] = fmaxf(acc, 0.f);
    }
    __syncthreads();
    if (t < 64) {
        float v = h2s[t] * dW3[t] + h2s[t + 64] * dW3[t + 64];
        #pragma unroll
        for (int off = 32; off > 0; off >>= 1) v += __shfl_xor(v, off);
        if (t == 0) preds[b] = v + db3[0];
    }
}

__global__ __launch_bounds__(64) void final_kernel(
    const float* __restrict__ accum, const float* __restrict__ preds,
    const int* __restrict__ y2_lens, const int* __restrict__ x2_lens,
    float* __restrict__ out)
{
    if (threadIdx.x == 0) {
        float dl = 0.f;
        for (int b = 0; b < BATCH; ++b) {
            float tgt = (float)y2_lens[b] / (float)x2_lens[b];
            float e = preds[b] - tgt;
            float ae = fabsf(e);
            dl += (ae <= 1.f) ? 0.5f * e * e : (ae - 0.5f);
        }
        dl *= (1.f / BATCH);
        float token_loss = accum[0] / accum[1];
        float acc_v = accum[2] / fmaxf(accum[3], 1.f);
        out[0] = token_loss + dl;
        out[1] = acc_v;
    }
}

// ---------------- orchestration ----------------
extern "C" void kernel_launch(void* const* d_in, const int* in_sizes, int n_in,
                              void* d_out, int out_size, void* d_ws, size_t ws_size,
                              hipStream_t stream)
{
    const int*   x           = (const int*)d_in[0];
    const int*   x1_lens     = (const int*)d_in[1];
    const int*   x2_lens     = (const int*)d_in[2];
    const int*   y           = (const int*)d_in[3];
    const int*   y1_lens     = (const int*)d_in[4];
    const int*   y2_lens     = (const int*)d_in[5];
    const int*   y_mask      = (const int*)d_in[6];
    const float* emo_feature = (const float*)d_in[7];
    const float* text_emb    = (const float*)d_in[8];
    const float* audio_emb   = (const float*)d_in[9];
    const float* type_emb    = (const float*)d_in[10];
    const float* emo_W       = (const float*)d_in[11];
    const float* emo_b       = (const float*)d_in[12];
    const float* alpha_text  = (const float*)d_in[13];
    const float* alpha_audio = (const float*)d_in[14];
    const float* Wqkv        = (const float*)d_in[15];
    const float* bqkv        = (const float*)d_in[16];
    const float* Wo          = (const float*)d_in[17];
    const float* bo          = (const float*)d_in[18];
    const float* ln1_g       = (const float*)d_in[19];
    const float* ln1_b       = (const float*)d_in[20];
    const float* ln2_g       = (const float*)d_in[21];
    const float* ln2_b       = (const float*)d_in[22];
    const float* W1          = (const float*)d_in[23];
    const float* b1          = (const float*)d_in[24];
    const float* W2          = (const float*)d_in[25];
    const float* b2          = (const float*)d_in[26];
    const float* predict_W   = (const float*)d_in[27];
    const float* dW1         = (const float*)d_in[28];
    const float* db1         = (const float*)d_in[29];
    const float* dW2         = (const float*)d_in[30];
    const float* db2         = (const float*)d_in[31];
    const float* dW3         = (const float*)d_in[32];
    const float* db3         = (const float*)d_in[33];

    const int M = BATCH * SEQ;                       // 4612
    char* p = (char*)d_ws;
    float* hbuf   = (float*)p; p += 9445376;         // M*512*4
    float* delta  = (float*)p; p += 9445376;
    char*  uni    = p;         p += 18909440;        // ff1_bf | logits lg0 | attn opart
    u16*   hbuf_bf = (u16*)p;  p += 4722688;
    u16*   qkv_bf  = (u16*)p;  p += 14168064;        // also split-K partial region
    u16*   obuf_bf = (u16*)p;  p += 4722688;
    u16*   wbf     = (u16*)p;  p += 19923968;
    u16*   cbuf    = (u16*)p;  p += (size_t)CCAP * DMODEL * 2;
    u16*   ff1_bf  = (u16*)uni;

    float* partA = (float*)qkv_bf;
    float* partB = (float*)((char*)qkv_bf + 9445376);
    float* lg0   = (float*)uni;
    float* lg1   = (float*)qkv_bf;
    float* opart = (float*)uni;                      // 2 x NROWS x 64 f32 (ff1 dead)
    float* mlbuf = delta;                            // 4 x NROWS f32 (delta dead during attn)

    float* accum  = delta;
    int*   cnt    = (int*)(delta + 4);
    float* preds  = delta + 8;
    int*   cmap   = (int*)(delta + 16);
    int*   ctgt   = cmap + CCAP;
    float* h1buf  = (float*)(ctgt + CCAP);

    u16* wq_bf = wbf;                                // 3*1536*512
    u16* wo_bf = wq_bf + 2359296;                    // 3*512*512
    u16* w1_bf = wo_bf + 786432;                     // 3*2048*512
    u16* w2_bf = w1_bf + 3145728;                    // 3*512*2048
    u16* wp_bf = w2_bf + 3145728;                    // 1025*512

    cvt5_kernel<<<1024, 256, 0, stream>>>(
        Wqkv, wq_bf, 2359296 / 4,
        Wo, wo_bf, 786432 / 4,
        W1, w1_bf, 3145728 / 4,
        W2, w2_bf, 3145728 / 4,
        predict_W, wp_bf, 524800 / 4);

    emo_kernel<<<32, 256, 0, stream>>>(emo_feature, emo_W, emo_b, type_emb, hbuf, hbuf_bf);
    build_h_kernel<<<M / 4, 256, 0, stream>>>(
        x, y, y_mask, text_emb, audio_emb, type_emb,
        alpha_text, alpha_audio, hbuf, hbuf_bf);

    const int MG = (M + 127) / 128;   // 37
    for (int l = 0; l < NLAYER; ++l) {
        gemm_bf16_kernel<<<dim3(12, MG), 512, 0, stream>>>(
            hbuf_bf, wq_bf + (size_t)l * 1536 * 512, bqkv + l * 1536,
            nullptr, qkv_bf, M, 1536, 512, 0);
        attn_mfma_kernel<<<dim3((SEQ + QBLK - 1) / QBLK, BATCH * NH, 2), 512, 0, stream>>>(
            qkv_bf, x1_lens, x2_lens, y1_lens, y2_lens, y_mask, opart, mlbuf);
        attn_merge_kernel<<<NROWS / 4, 256, 0, stream>>>(opart, mlbuf, obuf_bf);
        gemm_bf16_splitk_kernel<<<dim3(4, MG, 2), 512, 0, stream>>>(
            obuf_bf, wo_bf + (size_t)l * 512 * 512,
            delta, partA, nullptr, M, 512, 512, 256);
        add_ln_kernel<<<M / 4, 256, 0, stream>>>(hbuf, hbuf_bf,
            delta, partA, nullptr, bo + l * 512,
            ln1_g + l * DMODEL, ln1_b + l * DMODEL);
        gemm_bf16_kernel<<<dim3(16, MG), 512, 0, stream>>>(
            hbuf_bf, w1_bf + (size_t)l * 2048 * 512, b1 + l * 2048,
            nullptr, ff1_bf, M, 2048, 512, 1);
        gemm_bf16_splitk_kernel<<<dim3(4, MG, 3), 512, 0, stream>>>(
            ff1_bf, w2_bf + (size_t)l * 512 * 2048,
            delta, partA, partB, M, 512, 2048, 768);
        add_ln_kernel<<<M / 4, 256, 0, stream>>>(hbuf, hbuf_bf,
            delta, partA, partB, b2 + l * 512,
            ln2_g + l * DMODEL, ln2_b + l * DMODEL);
    }

    init_accum_kernel<<<1, 64, 0, stream>>>(accum);
    compact_kernel<<<(BATCH * YL) / 256, 256, 0, stream>>>(y_mask, cnt, cmap);
    copy_rows_kernel<<<CCAP, 256, 0, stream>>>(cnt, cmap, hbuf_bf, y, cbuf, ctgt);
    gemm_bf16_splitk_dynm_kernel<<<dim3((OV + 127) / 128, CCAP / 128, 2), 512, 0, stream>>>(
        cbuf, wp_bf, cnt, lg0, lg1, OV, 512, 256);
    ce_kernel<<<CCAP, 256, 0, stream>>>(cnt, lg0, lg1, ctgt, accum);

    dur1_kernel<<<32, 256, 0, stream>>>(hbuf, y1_lens, dW1, db1, h1buf);
    dur2_kernel<<<4, 256, 0, stream>>>(h1buf, dW2, db2, dW3, db3, preds);
    final_kernel<<<1, 64, 0, stream>>>(accum, preds, y2_lens, x2_lens, (float*)d_out);
}

// Round 12
// 518.266 us; speedup vs baseline: 1.4011x; 1.0181x over previous
//
#include <hip/hip_runtime.h>
#include <hip/hip_bf16.h>
#include <math.h>

#define BATCH 4
#define XL 128
#define YL 1024
#define DMODEL 512
#define NH 8
#define NLAYER 3
#define DFF 2048
#define MASK_ID 1024
#define EOS_TOK 1024
#define HD 64
#define SEQ 1153          // XL + 1 + YL
#define OV 1025
#define NEGBIG (-1e9f)
#define QBLK 64
#define CCAP 2432         // max compacted masked rows

typedef unsigned short u16;
typedef unsigned int u32;
typedef short short8 __attribute__((ext_vector_type(8)));
typedef float f32x4 __attribute__((ext_vector_type(4)));

__device__ __forceinline__ u16 f2bf(float f) {
    union { float f; unsigned u; } v; v.f = f;
    unsigned r = v.u + 0x7fffu + ((v.u >> 16) & 1u);   // RNE
    return (u16)(r >> 16);
}
__device__ __forceinline__ float bf2f(u16 b) {
    union { unsigned u; float f; } v; v.u = ((unsigned)b) << 16;
    return v.f;
}

// ---------------- fused f32 -> bf16 convert for all 5 weight tensors ----------------
__global__ __launch_bounds__(256) void cvt5_kernel(
    const float* __restrict__ s0, u16* __restrict__ d0, int n0,
    const float* __restrict__ s1, u16* __restrict__ d1, int n1,
    const float* __restrict__ s2, u16* __restrict__ d2, int n2,
    const float* __restrict__ s3, u16* __restrict__ d3, int n3,
    const float* __restrict__ s4, u16* __restrict__ d4, int n4)
{
    int c0 = n0, c1 = c0 + n1, c2 = c1 + n2, c3 = c2 + n3, c4 = c3 + n4;
    for (int i = blockIdx.x * 256 + threadIdx.x; i < c4; i += gridDim.x * 256) {
        const float* s; u16* d; int j;
        if (i < c0)      { s = s0; d = d0; j = i; }
        else if (i < c1) { s = s1; d = d1; j = i - c0; }
        else if (i < c2) { s = s2; d = d2; j = i - c1; }
        else if (i < c3) { s = s3; d = d3; j = i - c2; }
        else             { s = s4; d = d4; j = i - c3; }
        float4 v = ((const float4*)s)[j];
        ushort4 o;
        o.x = f2bf(v.x); o.y = f2bf(v.y); o.z = f2bf(v.z); o.w = f2bf(v.w);
        ((ushort4*)d)[j] = o;
    }
}

// ---------------- emo rows ----------------
__global__ __launch_bounds__(256) void emo_kernel(
    const float* __restrict__ emo_feature, const float* __restrict__ emo_W,
    const float* __restrict__ emo_b, const float* __restrict__ type_emb,
    float* __restrict__ hbuf, u16* __restrict__ hbuf_bf)
{
    int b = blockIdx.x >> 3, c = blockIdx.x & 7;
    int t = threadIdx.x;
    int osub = t >> 2, ln = t & 3;
    int d = c * 64 + osub;
    const float* f = emo_feature + b * 768 + ln * 192;
    const float* w = emo_W + (size_t)d * 768 + ln * 192;
    float acc = 0.f;
    #pragma unroll 4
    for (int k = 0; k < 192; ++k) acc = fmaf(f[k], w[k], acc);
    acc += __shfl_xor(acc, 1);
    acc += __shfl_xor(acc, 2);
    if (ln == 0) {
        float v = acc + emo_b[d] + type_emb[DMODEL + d];
        hbuf[(size_t)(b * SEQ + XL) * DMODEL + d] = v;
        hbuf_bf[(size_t)(b * SEQ + XL) * DMODEL + d] = f2bf(v);
    }
}

// ---------------- build h_input (x & y rows), wave-per-row ----------------
__global__ __launch_bounds__(256) void build_h_kernel(
    const int* __restrict__ x, const int* __restrict__ y, const int* __restrict__ y_mask,
    const float* __restrict__ text_emb, const float* __restrict__ audio_emb,
    const float* __restrict__ type_emb,
    const float* __restrict__ alpha_text, const float* __restrict__ alpha_audio,
    float* __restrict__ hbuf, u16* __restrict__ hbuf_bf)
{
    int row = blockIdx.x * 4 + (threadIdx.x >> 6);
    int l = threadIdx.x & 63;
    int b = row / SEQ, s = row % SEQ;
    if (s == XL) return;
    int d0 = l * 8;

    const float* emb; const float* te; float alpha; int pos;
    if (s < XL) {
        int tok = x[b * XL + s];
        emb = text_emb + (size_t)tok * DMODEL;
        te = type_emb; alpha = alpha_text[0]; pos = s;
    } else {
        int r = s - XL - 1;
        int tok = y_mask[b * YL + r] ? MASK_ID : y[b * YL + r];
        emb = audio_emb + (size_t)tok * DMODEL;
        te = type_emb + 2 * DMODEL; alpha = alpha_audio[0]; pos = r;
    }

    float4 e0 = *(const float4*)(emb + d0);
    float4 e1 = *(const float4*)(emb + d0 + 4);
    float4 t0 = *(const float4*)(te + d0);
    float4 t1 = *(const float4*)(te + d0 + 4);
    float v[8] = {e0.x + t0.x, e0.y + t0.y, e0.z + t0.z, e0.w + t0.w,
                  e1.x + t1.x, e1.y + t1.y, e1.z + t1.z, e1.w + t1.w};
    float fp = (float)pos;
    #pragma unroll
    for (int p = 0; p < 4; ++p) {
        int d = d0 + 2 * p;
        float div = __expf((float)d * (-9.210340371976184f / (float)DMODEL));
        float sn, cs;
        __sincosf(fp * div, &sn, &cs);
        v[2 * p]     += alpha * sn;
        v[2 * p + 1] += alpha * cs;
    }

    float* hp = hbuf + (size_t)row * DMODEL + d0;
    *(float4*)hp       = make_float4(v[0], v[1], v[2], v[3]);
    *(float4*)(hp + 4) = make_float4(v[4], v[5], v[6], v[7]);
    short8 sv;
    #pragma unroll
    for (int e = 0; e < 8; ++e) sv[e] = (short)f2bf(v[e]);
    *(short8*)(hbuf_bf + (size_t)row * DMODEL + d0) = sv;
}

// ======= bf16 MFMA NT GEMM, 128x128 tile, 8 waves (4x2), one gload_lds/thread =======
__global__ __launch_bounds__(512) void gemm_bf16_kernel(
    const u16* __restrict__ A, const u16* __restrict__ Bw,
    const float* __restrict__ bias,
    float* __restrict__ Cf, u16* __restrict__ Cb,
    int M, int N, int K, int relu)
{
    __shared__ u16 As[128 * 32];
    __shared__ u16 Bs[128 * 32];
    int tid = threadIdx.x;
    int w = tid >> 6, l = tid & 63;
    int m0 = blockIdx.y * 128, n0 = blockIdx.x * 128;
    int wm = (w >> 1) * 32, wn = (w & 1) * 64;

    f32x4 acc[2][4];
    #pragma unroll
    for (int i = 0; i < 2; ++i)
        #pragma unroll
        for (int j = 0; j < 4; ++j) acc[i][j] = (f32x4){0.f, 0.f, 0.f, 0.f};

    int srow = (w << 4) + (l >> 2);
    int skp = (l & 3) << 3;

    for (int k0 = 0; k0 < K; k0 += 32) {
        {
            int am = m0 + srow; if (am >= M) am = M - 1;
            int bn = n0 + srow; if (bn >= N) bn = N - 1;
            __builtin_amdgcn_global_load_lds(
                (const __attribute__((address_space(1))) void*)(A + (size_t)am * K + k0 + skp),
                (__attribute__((address_space(3))) void*)(As + (w << 9)), 16, 0, 0);
            __builtin_amdgcn_global_load_lds(
                (const __attribute__((address_space(1))) void*)(Bw + (size_t)bn * K + k0 + skp),
                (__attribute__((address_space(3))) void*)(Bs + (w << 9)), 16, 0, 0);
        }
        __syncthreads();
        short8 af[2], bfr[4];
        #pragma unroll
        for (int i = 0; i < 2; ++i)
            af[i]  = *(const short8*)(As + (wm + i * 16 + (l & 15)) * 32 + ((l >> 4) << 3));
        #pragma unroll
        for (int j = 0; j < 4; ++j)
            bfr[j] = *(const short8*)(Bs + (wn + j * 16 + (l & 15)) * 32 + ((l >> 4) << 3));
        #pragma unroll
        for (int i = 0; i < 2; ++i)
            #pragma unroll
            for (int j = 0; j < 4; ++j)
                acc[i][j] = __builtin_amdgcn_mfma_f32_16x16x32_bf16(af[i], bfr[j], acc[i][j], 0, 0, 0);
        __syncthreads();
    }

    #pragma unroll
    for (int i = 0; i < 2; ++i) {
        #pragma unroll
        for (int j = 0; j < 4; ++j) {
            #pragma unroll
            for (int jj = 0; jj < 4; ++jj) {
                int row = m0 + wm + i * 16 + ((l >> 4) << 2) + jj;
                int col = n0 + wn + j * 16 + (l & 15);
                if (row < M && col < N) {
                    float v = acc[i][j][jj];
                    if (bias) v += bias[col];
                    if (relu) v = fmaxf(v, 0.f);
                    if (Cf) Cf[(size_t)row * N + col] = v;
                    if (Cb) Cb[(size_t)row * N + col] = f2bf(v);
                }
            }
        }
    }
}

// ---- split-K variant (8-wave) ----
__global__ __launch_bounds__(512) void gemm_bf16_splitk_kernel(
    const u16* __restrict__ A, const u16* __restrict__ Bw,
    float* __restrict__ P0, float* __restrict__ P1, float* __restrict__ P2,
    int M, int N, int K, int klen)
{
    __shared__ u16 As[128 * 32];
    __shared__ u16 Bs[128 * 32];
    int tid = threadIdx.x;
    int w = tid >> 6, l = tid & 63;
    int z = blockIdx.z;
    float* Cp = (z == 0) ? P0 : (z == 1) ? P1 : P2;
    int kbeg = z * klen;
    int kend = min(kbeg + klen, K);
    int m0 = blockIdx.y * 128, n0 = blockIdx.x * 128;
    int wm = (w >> 1) * 32, wn = (w & 1) * 64;

    f32x4 acc[2][4];
    #pragma unroll
    for (int i = 0; i < 2; ++i)
        #pragma unroll
        for (int j = 0; j < 4; ++j) acc[i][j] = (f32x4){0.f, 0.f, 0.f, 0.f};

    int srow = (w << 4) + (l >> 2);
    int skp = (l & 3) << 3;

    for (int k0 = kbeg; k0 < kend; k0 += 32) {
        {
            int am = m0 + srow; if (am >= M) am = M - 1;
            int bn = n0 + srow; if (bn >= N) bn = N - 1;
            __builtin_amdgcn_global_load_lds(
                (const __attribute__((address_space(1))) void*)(A + (size_t)am * K + k0 + skp),
                (__attribute__((address_space(3))) void*)(As + (w << 9)), 16, 0, 0);
            __builtin_amdgcn_global_load_lds(
                (const __attribute__((address_space(1))) void*)(Bw + (size_t)bn * K + k0 + skp),
                (__attribute__((address_space(3))) void*)(Bs + (w << 9)), 16, 0, 0);
        }
        __syncthreads();
        short8 af[2], bfr[4];
        #pragma unroll
        for (int i = 0; i < 2; ++i)
            af[i]  = *(const short8*)(As + (wm + i * 16 + (l & 15)) * 32 + ((l >> 4) << 3));
        #pragma unroll
        for (int j = 0; j < 4; ++j)
            bfr[j] = *(const short8*)(Bs + (wn + j * 16 + (l & 15)) * 32 + ((l >> 4) << 3));
        #pragma unroll
        for (int i = 0; i < 2; ++i)
            #pragma unroll
            for (int j = 0; j < 4; ++j)
                acc[i][j] = __builtin_amdgcn_mfma_f32_16x16x32_bf16(af[i], bfr[j], acc[i][j], 0, 0, 0);
        __syncthreads();
    }

    #pragma unroll
    for (int i = 0; i < 2; ++i) {
        #pragma unroll
        for (int j = 0; j < 4; ++j) {
            #pragma unroll
            for (int jj = 0; jj < 4; ++jj) {
                int row = m0 + wm + i * 16 + ((l >> 4) << 2) + jj;
                int col = n0 + wn + j * 16 + (l & 15);
                if (row < M && col < N)
                    Cp[(size_t)row * N + col] = acc[i][j][jj];
            }
        }
    }
}

// ---- split-K + dynamic-M (logits, 8-wave) ----
__global__ __launch_bounds__(512) void gemm_bf16_splitk_dynm_kernel(
    const u16* __restrict__ A, const u16* __restrict__ Bw,
    const int* __restrict__ Mp,
    float* __restrict__ P0, float* __restrict__ P1,
    int N, int K, int klen)
{
    int M = *Mp;
    int m0 = blockIdx.y * 128;
    if (m0 >= M) return;
    __shared__ u16 As[128 * 32];
    __shared__ u16 Bs[128 * 32];
    int tid = threadIdx.x;
    int w = tid >> 6, l = tid & 63;
    int z = blockIdx.z;
    float* Cp = (z == 0) ? P0 : P1;
    int kbeg = z * klen;
    int kend = min(kbeg + klen, K);
    int n0 = blockIdx.x * 128;
    int wm = (w >> 1) * 32, wn = (w & 1) * 64;

    f32x4 acc[2][4];
    #pragma unroll
    for (int i = 0; i < 2; ++i)
        #pragma unroll
        for (int j = 0; j < 4; ++j) acc[i][j] = (f32x4){0.f, 0.f, 0.f, 0.f};

    int srow = (w << 4) + (l >> 2);
    int skp = (l & 3) << 3;

    for (int k0 = kbeg; k0 < kend; k0 += 32) {
        {
            int am = m0 + srow; if (am >= M) am = M - 1;
            int bn = n0 + srow; if (bn >= N) bn = N - 1;
            __builtin_amdgcn_global_load_lds(
                (const __attribute__((address_space(1))) void*)(A + (size_t)am * K + k0 + skp),
                (__attribute__((address_space(3))) void*)(As + (w << 9)), 16, 0, 0);
            __builtin_amdgcn_global_load_lds(
                (const __attribute__((address_space(1))) void*)(Bw + (size_t)bn * K + k0 + skp),
                (__attribute__((address_space(3))) void*)(Bs + (w << 9)), 16, 0, 0);
        }
        __syncthreads();
        short8 af[2], bfr[4];
        #pragma unroll
        for (int i = 0; i < 2; ++i)
            af[i]  = *(const short8*)(As + (wm + i * 16 + (l & 15)) * 32 + ((l >> 4) << 3));
        #pragma unroll
        for (int j = 0; j < 4; ++j)
            bfr[j] = *(const short8*)(Bs + (wn + j * 16 + (l & 15)) * 32 + ((l >> 4) << 3));
        #pragma unroll
        for (int i = 0; i < 2; ++i)
            #pragma unroll
            for (int j = 0; j < 4; ++j)
                acc[i][j] = __builtin_amdgcn_mfma_f32_16x16x32_bf16(af[i], bfr[j], acc[i][j], 0, 0, 0);
        __syncthreads();
    }

    #pragma unroll
    for (int i = 0; i < 2; ++i) {
        #pragma unroll
        for (int j = 0; j < 4; ++j) {
            #pragma unroll
            for (int jj = 0; jj < 4; ++jj) {
                int row = m0 + wm + i * 16 + ((l >> 4) << 2) + jj;
                int col = n0 + wn + j * 16 + (l & 15);
                if (row < M && col < N)
                    Cp[(size_t)row * N + col] = acc[i][j][jj];
            }
        }
    }
}

// ====== MFMA flash attention: QBLK=64, 8 waves, IN-BLOCK k-split (wave groups), ======
// ====== swapped QK^T, in-register softmax, LDS merge, direct bf16 output       ======
// grid (19, 32), 512 thr. Waves 0-3: front k-half for q-rows 16wq..; waves 4-7: back.
__global__ __launch_bounds__(512) void attn_mfma_kernel(
    const u16* __restrict__ qkv,
    const int* __restrict__ x1_lens, const int* __restrict__ x2_lens,
    const int* __restrict__ y1_lens, const int* __restrict__ y2_lens,
    const int* __restrict__ y_mask,
    u16* __restrict__ obuf)
{
    __shared__ u16 Ks[2][64 * 64];              // per-group K tile, XOR-swizzled
    __shared__ u16 Vt[2][64 * 64];              // per-group V^T tile, XOR-swizzled
    __shared__ unsigned long long Bits[7][19];
    __shared__ float Om[4][16][65];             // back-group O for merge (pad 65)
    __shared__ float MLm[4][2][16];             // back-group m,l

    int tid = threadIdx.x;
    int w = tid >> 6, l = tid & 63;
    int grp = w >> 2;               // 0 = front k-half, 1 = back k-half
    int wq = w & 3;                 // q sub-tile (16 rows each)
    int ti = tid & 255;             // thread id within group
    int g = l >> 4;                 // lane group 0..3
    int q = l & 15;                 // q-row within sub-tile
    int bh = blockIdx.y;
    int b = bh >> 3, h = bh & 7;
    int q0 = (gridDim.x - 1 - blockIdx.x) * QBLK;   // heavy tiles first

    int x1 = x1_lens[b], xlen = x1 + 1 + x2_lens[b];
    int y1 = y1_lens[b], ylen = y1 + 1 + y2_lens[b];

    // ---- block-level kmax over alive rows (dead blocks process 1 masked tile) ----
    int kmax = -1;
    if (q0 < XL) kmax = max(kmax, xlen - 1);
    if (XL >= q0 && XL < q0 + QBLK) kmax = max(kmax, XL);
    {
        int ry0 = max(0, q0 - XL - 1);
        int ry1 = min(YL - 1, q0 + QBLK - 2 - XL);
        if (ry0 <= ry1) {
            if (ry0 <= y1 - 1) kmax = max(kmax, XL + y1);
            if (y1 >= ry0 && y1 <= ry1) kmax = max(kmax, XL + y1 + 1);
            int a = max(ry0, y1 + 1), bb = min(ry1, ylen - 1);
            if (a <= bb) kmax = max(kmax, XL + ylen);
        }
    }
    if (kmax < 0) kmax = 0;
    int NKT = (kmax >> 6) + 1;
    int h0 = (NKT + 1) >> 1;
    int kbeg = grp ? h0 : 0;
    int kend = grp ? NKT : h0;

    // ---- allow bitmaps via wave ballot ----
    for (int pp = w; pp < 7 * 19; pp += 8) {
        int ty = pp / 19, tile = pp - ty * 19;
        int c = tile * 64 + l;
        bool allow = false;
        if (c < SEQ && ty < 6) {
            bool a2c = (c == XL), ygt = (c > XL);
            if (ty == 0) allow = (c < x1);
            else if (ty == 1) allow = (c >= x1) && (c < xlen);
            else if (ty == 2) allow = a2c;
            else if (ty == 3) allow = (c < x1) || (ygt && c <= XL + y1);
            else if (ty == 4) allow = (c < xlen) || a2c || (ygt && c <= XL + y1 + 1);
            else {
                int ym = ygt ? y_mask[b * YL + c - XL - 1] : 0;
                allow = (((c < xlen) || a2c || (ygt && c <= XL + ylen)) && !ym);
            }
        }
        unsigned long long mk = __ballot(allow);
        if (l == 0) Bits[ty][tile] = mk;
    }

    // ---- Q fragment (row q0 + 16wq + q), scale 1/8 folded in ----
    int qr = q0 + wq * 16 + q;
    int qrc = min(qr, SEQ - 1);
    short8 qf0, qf1;
    {
        const u16* qp = qkv + (size_t)(b * SEQ + qrc) * 1536 + h * 64 + (g << 3);
        short8 r0 = *(const short8*)qp;
        short8 r1 = *(const short8*)(qp + 32);
        #pragma unroll
        for (int e = 0; e < 8; ++e) {
            qf0[e] = (short)f2bf(bf2f((u16)r0[e]) * 0.125f);
            qf1[e] = (short)f2bf(bf2f((u16)r1[e]) * 0.125f);
        }
    }

    // ---- row type of this lane's q ----
    int rt;
    {
        if (qr >= SEQ) rt = 6;
        else if (qr < XL) rt = (qr < x1) ? 0 : 1;
        else if (qr == XL) rt = 2;
        else {
            int ry = qr - XL - 1;
            rt = (ry < y1) ? 3 : (ry == y1) ? 4 : (ry < ylen) ? 5 : 6;
        }
    }

    f32x4 oacc[4];
    #pragma unroll
    for (int db = 0; db < 4; ++db) oacc[db] = (f32x4){0.f, 0.f, 0.f, 0.f};
    float mrun = -INFINITY, lrun = 0.f;

    int srcA = q + ((g & 1) << 5);
    int srcB = srcA + 16;
    bool hi = (g >> 1) & 1;

    for (int i = 0; i < h0; ++i) {
        int kt = kbeg + i;
        bool act = kt < kend;
        __syncthreads();
        if (act) {
            // ---- stage K tile into Ks[grp] (256 thr, 2x b128 each) ----
            #pragma unroll
            for (int ii = 0; ii < 2; ++ii) {
                int idx = ti + (ii << 8);
                int r = idx >> 3, d0k = (idx & 7) << 3;
                int krc = min(kt * 64 + r, SEQ - 1);
                short8 ka = *(const short8*)(qkv + (size_t)(b * SEQ + krc) * 1536 + 512 + h * 64 + d0k);
                *(short8*)&Ks[grp][r * 64 + (d0k ^ ((r & 7) << 3))] = ka;
            }
            // ---- stage V^T into Vt[grp] (256 thr, 2 iters of paired u32) ----
            #pragma unroll
            for (int ii = 0; ii < 2; ++ii) {
                int idx = ti + (ii << 8);
                int rp = idx >> 4, o = idx & 15;
                int d0v = o * 4;
                int k0r = min(kt * 64 + 2 * rp, SEQ - 1);
                int k1r = min(kt * 64 + 2 * rp + 1, SEQ - 1);
                ushort4 va = *(const ushort4*)(qkv + (size_t)(b * SEQ + k0r) * 1536 + 1024 + h * 64 + d0v);
                ushort4 vb = *(const ushort4*)(qkv + (size_t)(b * SEQ + k1r) * 1536 + 1024 + h * 64 + d0v);
                u32 pv[4] = {(u32)va.x | ((u32)vb.x << 16), (u32)va.y | ((u32)vb.y << 16),
                             (u32)va.z | ((u32)vb.z << 16), (u32)va.w | ((u32)vb.w << 16)};
                #pragma unroll
                for (int e = 0; e < 4; ++e) {
                    int d = d0v + e;
                    *(u32*)&Vt[grp][d * 64 + ((2 * rp) ^ ((d & 7) << 3))] = pv[e];
                }
            }
        }
        __syncthreads();
        if (!act) continue;

        // ---- QK^T swapped ----
        f32x4 sc[4];
        #pragma unroll
        for (int cb = 0; cb < 4; ++cb) {
            int krw = cb * 16 + q;
            int ksw = (krw & 7) << 3;
            short8 k0 = *(const short8*)&Ks[grp][krw * 64 + ((g << 3) ^ ksw)];
            short8 k1 = *(const short8*)&Ks[grp][krw * 64 + ((32 + (g << 3)) ^ ksw)];
            f32x4 zz = (f32x4){0.f, 0.f, 0.f, 0.f};
            zz = __builtin_amdgcn_mfma_f32_16x16x32_bf16(k0, qf0, zz, 0, 0, 0);
            sc[cb] = __builtin_amdgcn_mfma_f32_16x16x32_bf16(k1, qf1, zz, 0, 0, 0);
        }

        // ---- mask ----
        unsigned long long mb = Bits[rt][kt];
        #pragma unroll
        for (int cb = 0; cb < 4; ++cb) {
            unsigned nib = (unsigned)(mb >> (16 * cb + 4 * g)) & 0xFu;
            #pragma unroll
            for (int r = 0; r < 4; ++r)
                sc[cb][r] = ((nib >> r) & 1u) ? sc[cb][r] : NEGBIG;
        }

        // ---- online softmax ----
        float tmax = sc[0][0];
        #pragma unroll
        for (int cb = 0; cb < 4; ++cb)
            #pragma unroll
            for (int r = 0; r < 4; ++r) tmax = fmaxf(tmax, sc[cb][r]);
        tmax = fmaxf(tmax, __shfl_xor(tmax, 16));
        tmax = fmaxf(tmax, __shfl_xor(tmax, 32));
        float newm = fmaxf(mrun, tmax);
        float corr = __expf(mrun - newm);
        float p[4][4];
        float ps = 0.f;
        #pragma unroll
        for (int cb = 0; cb < 4; ++cb)
            #pragma unroll
            for (int r = 0; r < 4; ++r) {
                p[cb][r] = __expf(sc[cb][r] - newm);
                ps += p[cb][r];
            }
        ps += __shfl_xor(ps, 16);
        ps += __shfl_xor(ps, 32);
        lrun = lrun * corr + ps;
        mrun = newm;

        float cr[4];
        #pragma unroll
        for (int r = 0; r < 4; ++r) cr[r] = __shfl(corr, (g << 2) + r);
        #pragma unroll
        for (int db = 0; db < 4; ++db)
            #pragma unroll
            for (int r = 0; r < 4; ++r) oacc[db][r] *= cr[r];

        u32 P0[4], P1[4];
        #pragma unroll
        for (int cb = 0; cb < 4; ++cb) {
            P0[cb] = (u32)f2bf(p[cb][0]) | ((u32)f2bf(p[cb][1]) << 16);
            P1[cb] = (u32)f2bf(p[cb][2]) | ((u32)f2bf(p[cb][3]) << 16);
        }

        union { u32 u[4]; short8 s; } f1, f2;
        {
            u32 a0 = __shfl(P0[0], srcA), a1 = __shfl(P1[0], srcA);
            u32 a2 = __shfl(P0[0], srcB), a3 = __shfl(P1[0], srcB);
            u32 b0 = __shfl(P0[1], srcA), b1 = __shfl(P1[1], srcA);
            u32 b2 = __shfl(P0[1], srcB), b3 = __shfl(P1[1], srcB);
            f1.u[0] = hi ? b0 : a0; f1.u[1] = hi ? b1 : a1;
            f1.u[2] = hi ? b2 : a2; f1.u[3] = hi ? b3 : a3;
            u32 c0 = __shfl(P0[2], srcA), c1 = __shfl(P1[2], srcA);
            u32 c2 = __shfl(P0[2], srcB), c3 = __shfl(P1[2], srcB);
            u32 d0 = __shfl(P0[3], srcA), d1 = __shfl(P1[3], srcA);
            u32 d2 = __shfl(P0[3], srcB), d3 = __shfl(P1[3], srcB);
            f2.u[0] = hi ? d0 : c0; f2.u[1] = hi ? d1 : c1;
            f2.u[2] = hi ? d2 : c2; f2.u[3] = hi ? d3 : c3;
        }

        #pragma unroll
        for (int db = 0; db < 4; ++db) {
            int vr = db * 16 + q;
            int vsw = (vr & 7) << 3;
            short8 v0 = *(const short8*)&Vt[grp][vr * 64 + ((g << 3) ^ vsw)];
            short8 v1 = *(const short8*)&Vt[grp][vr * 64 + ((32 + (g << 3)) ^ vsw)];
            oacc[db] = __builtin_amdgcn_mfma_f32_16x16x32_bf16(f1.s, v0, oacc[db], 0, 0, 0);
            oacc[db] = __builtin_amdgcn_mfma_f32_16x16x32_bf16(f2.s, v1, oacc[db], 0, 0, 0);
        }
    }

    // ---- in-LDS merge: back group publishes, front group combines + writes ----
    __syncthreads();
    if (grp == 1) {
        #pragma unroll
        for (int db = 0; db < 4; ++db)
            #pragma unroll
            for (int r = 0; r < 4; ++r)
                Om[wq][(g << 2) + r][db * 16 + q] = oacc[db][r];
        if (g == 0) { MLm[wq][0][q] = mrun; MLm[wq][1][q] = lrun; }
    }
    __syncthreads();
    if (grp == 0) {
        float mB = MLm[wq][0][q], lB = MLm[wq][1][q];
        float M = fmaxf(mrun, mB);
        float wA = __expf(mrun - M), wB = __expf(mB - M);
        float denom = wA * lrun + wB * lB;
        float wAr[4], wBr[4], dr[4];
        #pragma unroll
        for (int r = 0; r < 4; ++r) {
            int src = (g << 2) + r;
            wAr[r] = __shfl(wA, src);
            wBr[r] = __shfl(wB, src);
            dr[r]  = 1.f / __shfl(denom, src);
        }
        #pragma unroll
        for (int db = 0; db < 4; ++db) {
            #pragma unroll
            for (int r = 0; r < 4; ++r) {
                int qrj = q0 + wq * 16 + (g << 2) + r;
                if (qrj < SEQ) {
                    float ov = (wAr[r] * oacc[db][r] +
                                wBr[r] * Om[wq][(g << 2) + r][db * 16 + q]) * dr[r];
                    obuf[(size_t)(b * SEQ + qrj) * DMODEL + h * 64 + db * 16 + q] = f2bf(ov);
                }
            }
        }
    }
}

// ------- residual add + fused split-K reduce (+bias) + LayerNorm, wave-per-row -------
__global__ __launch_bounds__(256) void add_ln_kernel(
    float* __restrict__ hbuf, u16* __restrict__ hbuf_bf,
    const float* __restrict__ p0, const float* __restrict__ p1,
    const float* __restrict__ p2, const float* __restrict__ bias,
    const float* __restrict__ g, const float* __restrict__ beta)
{
    int row = blockIdx.x * 4 + (threadIdx.x >> 6);
    int l = threadIdx.x & 63;
    int d0 = l * 8;
    size_t off = (size_t)row * DMODEL + d0;
    float* hp = hbuf + off;
    float4 a0 = *(const float4*)hp, a1 = *(const float4*)(hp + 4);
    float4 q0 = *(const float4*)(p0 + off), q1 = *(const float4*)(p0 + off + 4);
    float v[8] = {a0.x + q0.x, a0.y + q0.y, a0.z + q0.z, a0.w + q0.w,
                  a1.x + q1.x, a1.y + q1.y, a1.z + q1.z, a1.w + q1.w};
    if (p1) {
        float4 r0 = *(const float4*)(p1 + off), r1 = *(const float4*)(p1 + off + 4);
        v[0] += r0.x; v[1] += r0.y; v[2] += r0.z; v[3] += r0.w;
        v[4] += r1.x; v[5] += r1.y; v[6] += r1.z; v[7] += r1.w;
    }
    if (p2) {
        float4 r0 = *(const float4*)(p2 + off), r1 = *(const float4*)(p2 + off + 4);
        v[0] += r0.x; v[1] += r0.y; v[2] += r0.z; v[3] += r0.w;
        v[4] += r1.x; v[5] += r1.y; v[6] += r1.z; v[7] += r1.w;
    }
    {
        float4 b0 = *(const float4*)(bias + d0), b1 = *(const float4*)(bias + d0 + 4);
        v[0] += b0.x; v[1] += b0.y; v[2] += b0.z; v[3] += b0.w;
        v[4] += b1.x; v[5] += b1.y; v[6] += b1.z; v[7] += b1.w;
    }
    float s = 0.f;
    #pragma unroll
    for (int e = 0; e < 8; ++e) s += v[e];
    #pragma unroll
    for (int off2 = 32; off2 > 0; off2 >>= 1) s += __shfl_xor(s, off2);
    float mu = s * (1.f / DMODEL);
    float sq = 0.f;
    #pragma unroll
    for (int e = 0; e < 8; ++e) { v[e] -= mu; sq += v[e] * v[e]; }
    #pragma unroll
    for (int off2 = 32; off2 > 0; off2 >>= 1) sq += __shfl_xor(sq, off2);
    float inv = 1.f / sqrtf(sq * (1.f / DMODEL) + 1e-5f);
    float4 g0 = *(const float4*)(g + d0), g1 = *(const float4*)(g + d0 + 4);
    float4 be0 = *(const float4*)(beta + d0), be1 = *(const float4*)(beta + d0 + 4);
    float o[8];
    o[0] = v[0] * inv * g0.x + be0.x; o[1] = v[1] * inv * g0.y + be0.y;
    o[2] = v[2] * inv * g0.z + be0.z; o[3] = v[3] * inv * g0.w + be0.w;
    o[4] = v[4] * inv * g1.x + be1.x; o[5] = v[5] * inv * g1.y + be1.y;
    o[6] = v[6] * inv * g1.z + be1.z; o[7] = v[7] * inv * g1.w + be1.w;
    *(float4*)hp       = make_float4(o[0], o[1], o[2], o[3]);
    *(float4*)(hp + 4) = make_float4(o[4], o[5], o[6], o[7]);
    short8 sv;
    #pragma unroll
    for (int e = 0; e < 8; ++e) sv[e] = (short)f2bf(o[e]);
    *(short8*)(hbuf_bf + off) = sv;
}

// ---------------- compaction of masked rows ----------------
__global__ __launch_bounds__(256) void init_accum_kernel(float* accum) {
    if (threadIdx.x < 8) accum[threadIdx.x] = 0.f;
}

__global__ __launch_bounds__(256) void compact_kernel(
    const int* __restrict__ y_mask, int* __restrict__ cnt, int* __restrict__ cmap)
{
    int i = blockIdx.x * 256 + threadIdx.x;
    if (i < BATCH * YL && y_mask[i]) {
        int pos = atomicAdd(cnt, 1);
        cmap[pos] = i;
    }
}

__global__ __launch_bounds__(256) void copy_rows_kernel(
    const int* __restrict__ cnt, const int* __restrict__ cmap,
    const u16* __restrict__ hbuf_bf, const int* __restrict__ y,
    u16* __restrict__ cbuf, int* __restrict__ ctgt)
{
    int i = blockIdx.x;
    if (i >= *cnt) return;
    int g = cmap[i];
    int b = g >> 10, r = g & 1023;
    const u16* src = hbuf_bf + (size_t)(b * SEQ + XL + 1 + r) * DMODEL;
    u16* dst = cbuf + (size_t)i * DMODEL;
    int t = threadIdx.x;
    ((ushort2*)dst)[t] = ((const ushort2*)src)[t];
    if (t == 0) ctgt[i] = y[g];
}

// ---------------- CE + top-3 over compacted rows (sums 2 logits partials) ----------------
__global__ __launch_bounds__(256) void ce_kernel(
    const int* __restrict__ cnt,
    const float* __restrict__ lg0, const float* __restrict__ lg1,
    const int* __restrict__ ctgt, float* __restrict__ accum)
{
    int row = blockIdx.x;
    if (row >= *cnt) return;
    const float* lp0 = lg0 + (size_t)row * OV;
    const float* lp1 = lg1 + (size_t)row * OV;
    int tgt = ctgt[row];
    int t = threadIdx.x;
    __shared__ float red[4];

    float lmax = -INFINITY;
    for (int i = t; i < OV; i += 256) lmax = fmaxf(lmax, lp0[i] + lp1[i]);
    #pragma unroll
    for (int off = 32; off > 0; off >>= 1) lmax = fmaxf(lmax, __shfl_xor(lmax, off));
    if ((t & 63) == 0) red[t >> 6] = lmax;
    __syncthreads();
    lmax = fmaxf(fmaxf(red[0], red[1]), fmaxf(red[2], red[3]));
    __syncthreads();

    float lsum = 0.f;
    for (int i = t; i < OV; i += 256) lsum += expf(lp0[i] + lp1[i] - lmax);
    #pragma unroll
    for (int off = 32; off > 0; off >>= 1) lsum += __shfl_xor(lsum, off);
    if ((t & 63) == 0) red[t >> 6] = lsum;
    __syncthreads();
    lsum = red[0] + red[1] + red[2] + red[3];
    __syncthreads();

    float lt = lp0[tgt] + lp1[tgt];
    float cntr = 0.f;
    for (int i = t; i < OV; i += 256) {
        float v = lp0[i] + lp1[i];
        if (v > lt || (v == lt && i < tgt)) cntr += 1.f;
    }
    #pragma unroll
    for (int off = 32; off > 0; off >>= 1) cntr += __shfl_xor(cntr, off);
    if ((t & 63) == 0) red[t >> 6] = cntr;
    __syncthreads();
    cntr = red[0] + red[1] + red[2] + red[3];

    if (t == 0) {
        float ce = -(lt - lmax - logf(lsum));
        float inc = (tgt != EOS_TOK) ? 1.f : 0.f;
        float corr = (cntr < 2.5f) ? 1.f : 0.f;
        atomicAdd(&accum[0], ce);
        atomicAdd(&accum[1], 1.f);
        atomicAdd(&accum[2], corr * inc);
        atomicAdd(&accum[3], inc);
    }
}

// ---------------- duration head ----------------
__global__ __launch_bounds__(256) void dur1_kernel(
    const float* __restrict__ hbuf, const int* __restrict__ y1_lens,
    const float* __restrict__ dW1, const float* __restrict__ db1,
    float* __restrict__ h1buf)
{
    __shared__ float cls[DMODEL];
    int g = blockIdx.x;
    int b = g >> 3, c = g & 7;
    int t = threadIdx.x;
    const float* cp = hbuf + (size_t)(b * SEQ + XL + 1 + y1_lens[b]) * DMODEL;
    cls[t] = cp[t]; cls[t + 256] = cp[t + 256];
    __syncthreads();
    int row = c * 32 + (t >> 3);
    int ln = t & 7;
    const float* w = dW1 + (size_t)row * DMODEL + ln * 64;
    const float* cv = cls + ln * 64;
    float acc = 0.f;
    #pragma unroll 8
    for (int k = 0; k < 64; ++k) acc = fmaf(cv[k], w[k], acc);
    acc += __shfl_xor(acc, 1); acc += __shfl_xor(acc, 2); acc += __shfl_xor(acc, 4);
    if (ln == 0) h1buf[b * 256 + row] = fmaxf(acc + db1[row], 0.f);
}

__global__ __launch_bounds__(256) void dur2_kernel(
    const float* __restrict__ h1buf,
    const float* __restrict__ dW2, const float* __restrict__ db2,
    const float* __restrict__ dW3, const float* __restrict__ db3,
    float* __restrict__ preds)
{
    __shared__ float h1s[256];
    __shared__ float h2s[128];
    int b = blockIdx.x;
    int t = threadIdx.x;
    h1s[t] = h1buf[b * 256 + t];
    __syncthreads();
    if (t < 128) {
        float acc = db2[t];
        const float* w = dW2 + (size_t)t * 256;
        for (int k = 0; k < 256; ++k) acc = fmaf(h1s[k], w[k], acc);
        h2s[t] = fmaxf(acc, 0.f);
    }
    __syncthreads();
    if (t < 64) {
        float v = h2s[t] * dW3[t] + h2s[t + 64] * dW3[t + 64];
        #pragma unroll
        for (int off = 32; off > 0; off >>= 1) v += __shfl_xor(v, off);
        if (t == 0) preds[b] = v + db3[0];
    }
}

__global__ __launch_bounds__(64) void final_kernel(
    const float* __restrict__ accum, const float* __restrict__ preds,
    const int* __restrict__ y2_lens, const int* __restrict__ x2_lens,
    float* __restrict__ out)
{
    if (threadIdx.x == 0) {
        float dl = 0.f;
        for (int b = 0; b < BATCH; ++b) {
            float tgt = (float)y2_lens[b] / (float)x2_lens[b];
            float e = preds[b] - tgt;
            float ae = fabsf(e);
            dl += (ae <= 1.f) ? 0.5f * e * e : (ae - 0.5f);
        }
        dl *= (1.f / BATCH);
        float token_loss = accum[0] / accum[1];
        float acc_v = accum[2] / fmaxf(accum[3], 1.f);
        out[0] = token_loss + dl;
        out[1] = acc_v;
    }
}

// ---------------- orchestration ----------------
extern "C" void kernel_launch(void* const* d_in, const int* in_sizes, int n_in,
                              void* d_out, int out_size, void* d_ws, size_t ws_size,
                              hipStream_t stream)
{
    const int*   x           = (const int*)d_in[0];
    const int*   x1_lens     = (const int*)d_in[1];
    const int*   x2_lens     = (const int*)d_in[2];
    const int*   y           = (const int*)d_in[3];
    const int*   y1_lens     = (const int*)d_in[4];
    const int*   y2_lens     = (const int*)d_in[5];
    const int*   y_mask      = (const int*)d_in[6];
    const float* emo_feature = (const float*)d_in[7];
    const float* text_emb    = (const float*)d_in[8];
    const float* audio_emb   = (const float*)d_in[9];
    const float* type_emb    = (const float*)d_in[10];
    const float* emo_W       = (const float*)d_in[11];
    const float* emo_b       = (const float*)d_in[12];
    const float* alpha_text  = (const float*)d_in[13];
    const float* alpha_audio = (const float*)d_in[14];
    const float* Wqkv        = (const float*)d_in[15];
    const float* bqkv        = (const float*)d_in[16];
    const float* Wo          = (const float*)d_in[17];
    const float* bo          = (const float*)d_in[18];
    const float* ln1_g       = (const float*)d_in[19];
    const float* ln1_b       = (const float*)d_in[20];
    const float* ln2_g       = (const float*)d_in[21];
    const float* ln2_b       = (const float*)d_in[22];
    const float* W1          = (const float*)d_in[23];
    const float* b1          = (const float*)d_in[24];
    const float* W2          = (const float*)d_in[25];
    const float* b2          = (const float*)d_in[26];
    const float* predict_W   = (const float*)d_in[27];
    const float* dW1         = (const float*)d_in[28];
    const float* db1         = (const float*)d_in[29];
    const float* dW2         = (const float*)d_in[30];
    const float* db2         = (const float*)d_in[31];
    const float* dW3         = (const float*)d_in[32];
    const float* db3         = (const float*)d_in[33];

    const int M = BATCH * SEQ;                       // 4612
    char* p = (char*)d_ws;
    float* hbuf   = (float*)p; p += 9445376;         // M*512*4
    float* delta  = (float*)p; p += 9445376;
    char*  uni    = p;         p += 18909440;        // ff1_bf | logits lg0
    u16*   hbuf_bf = (u16*)p;  p += 4722688;
    u16*   qkv_bf  = (u16*)p;  p += 14168064;        // also split-K partial region
    u16*   obuf_bf = (u16*)p;  p += 4722688;
    u16*   wbf     = (u16*)p;  p += 19923968;
    u16*   cbuf    = (u16*)p;  p += (size_t)CCAP * DMODEL * 2;
    u16*   ff1_bf  = (u16*)uni;

    float* partA = (float*)qkv_bf;
    float* partB = (float*)((char*)qkv_bf + 9445376);
    float* lg0   = (float*)uni;
    float* lg1   = (float*)qkv_bf;

    float* accum  = delta;
    int*   cnt    = (int*)(delta + 4);
    float* preds  = delta + 8;
    int*   cmap   = (int*)(delta + 16);
    int*   ctgt   = cmap + CCAP;
    float* h1buf  = (float*)(ctgt + CCAP);

    u16* wq_bf = wbf;                                // 3*1536*512
    u16* wo_bf = wq_bf + 2359296;                    // 3*512*512
    u16* w1_bf = wo_bf + 786432;                     // 3*2048*512
    u16* w2_bf = w1_bf + 3145728;                    // 3*512*2048
    u16* wp_bf = w2_bf + 3145728;                    // 1025*512

    cvt5_kernel<<<1024, 256, 0, stream>>>(
        Wqkv, wq_bf, 2359296 / 4,
        Wo, wo_bf, 786432 / 4,
        W1, w1_bf, 3145728 / 4,
        W2, w2_bf, 3145728 / 4,
        predict_W, wp_bf, 524800 / 4);

    emo_kernel<<<32, 256, 0, stream>>>(emo_feature, emo_W, emo_b, type_emb, hbuf, hbuf_bf);
    build_h_kernel<<<M / 4, 256, 0, stream>>>(
        x, y, y_mask, text_emb, audio_emb, type_emb,
        alpha_text, alpha_audio, hbuf, hbuf_bf);

    const int MG = (M + 127) / 128;   // 37
    for (int l = 0; l < NLAYER; ++l) {
        gemm_bf16_kernel<<<dim3(12, MG), 512, 0, stream>>>(
            hbuf_bf, wq_bf + (size_t)l * 1536 * 512, bqkv + l * 1536,
            nullptr, qkv_bf, M, 1536, 512, 0);
        attn_mfma_kernel<<<dim3((SEQ + QBLK - 1) / QBLK, BATCH * NH), 512, 0, stream>>>(
            qkv_bf, x1_lens, x2_lens, y1_lens, y2_lens, y_mask, obuf_bf);
        gemm_bf16_splitk_kernel<<<dim3(4, MG, 2), 512, 0, stream>>>(
            obuf_bf, wo_bf + (size_t)l * 512 * 512,
            delta, partA, nullptr, M, 512, 512, 256);
        add_ln_kernel<<<M / 4, 256, 0, stream>>>(hbuf, hbuf_bf,
            delta, partA, nullptr, bo + l * 512,
            ln1_g + l * DMODEL, ln1_b + l * DMODEL);
        gemm_bf16_kernel<<<dim3(16, MG), 512, 0, stream>>>(
            hbuf_bf, w1_bf + (size_t)l * 2048 * 512, b1 + l * 2048,
            nullptr, ff1_bf, M, 2048, 512, 1);
        gemm_bf16_splitk_kernel<<<dim3(4, MG, 3), 512, 0, stream>>>(
            ff1_bf, w2_bf + (size_t)l * 512 * 2048,
            delta, partA, partB, M, 512, 2048, 768);
        add_ln_kernel<<<M / 4, 256, 0, stream>>>(hbuf, hbuf_bf,
            delta, partA, partB, b2 + l * 512,
            ln2_g + l * DMODEL, ln2_b + l * DMODEL);
    }

    init_accum_kernel<<<1, 64, 0, stream>>>(accum);
    compact_kernel<<<(BATCH * YL) / 256, 256, 0, stream>>>(y_mask, cnt, cmap);
    copy_rows_kernel<<<CCAP, 256, 0, stream>>>(cnt, cmap, hbuf_bf, y, cbuf, ctgt);
    gemm_bf16_splitk_dynm_kernel<<<dim3((OV + 127) / 128, CCAP / 128, 2), 512, 0, stream>>>(
        cbuf, wp_bf, cnt, lg0, lg1, OV, 512, 256);
    ce_kernel<<<CCAP, 256, 0, stream>>>(cnt, lg0, lg1, ctgt, accum);

    dur1_kernel<<<32, 256, 0, stream>>>(hbuf, y1_lens, dW1, db1, h1buf);
    dur2_kernel<<<4, 256, 0, stream>>>(h1buf, dW2, db2, dW3, db3, preds);
    final_kernel<<<1, 64, 0, stream>>>(accum, preds, y2_lens, x2_lens, (float*)d_out);
}